// Round 12
// baseline (362.642 us; speedup 1.0000x reference)
//
#include <hip/hip_runtime.h>
#include <math.h>

#define NN   128
#define SS   129          // LDS row stride in float2 (ODD -> conflict-free lane stride)
#define TT   512          // PROVEN: TT=512 allocates ~112-128 VGPR no-spill (R4/R6-R9);
                          // TT=1024 ALWAYS gets 64 VGPR + spill (R2/R3/R10). Never 1024.
#define NPIX 16384        // 128*128
#define EPT  32           // NPIX / TT
#define SG   65           // 64-grid row stride (float2 or float4 units)

__device__ __forceinline__ float2 cmul(float2 a, float2 w) {
    return make_float2(a.x * w.x - a.y * w.y, a.x * w.y + a.y * w.x);
}
__device__ __forceinline__ float2 cmulc(float2 a, float2 w) {   // a * conj(w)
    return make_float2(a.x * w.x + a.y * w.y, a.y * w.x - a.x * w.y);
}

// ---------- register FFT codelets (verified R2-R11) ----------
template<int SGN>
__device__ __forceinline__ void fft8(float2* f) {
    const float R = 0.70710678118654752f;
    const float WC[4] = {1.f, R, 0.f, -R};
    const float WS[4] = {0.f, R, 1.f, R};
    #pragma unroll
    for (int stage = 0; stage < 3; ++stage) {
        const int L = 8 >> stage, half = L >> 1, step = 1 << stage;
        #pragma unroll
        for (int base = 0; base < 8; base += L) {
            #pragma unroll
            for (int j = 0; j < half; ++j) {
                float2 u = f[base + j], v = f[base + half + j];
                f[base + j] = make_float2(u.x + v.x, u.y + v.y);
                float dx = u.x - v.x, dy = u.y - v.y;
                const int t = j * step;
                const float wr = WC[t];
                const float wi = (SGN > 0) ? WS[t] : -WS[t];
                f[base + half + j] = make_float2(dx * wr - dy * wi, dx * wi + dy * wr);
            }
        }
    }
    float2 tmp;
    tmp = f[1]; f[1] = f[4]; f[4] = tmp;
    tmp = f[3]; f[3] = f[6]; f[6] = tmp;
}

template<int SGN>
__device__ __forceinline__ void fft16(float2* f) {
    const float WC[8] = {1.f, 0.92387953251f, 0.70710678119f, 0.38268343236f,
                         0.f, -0.38268343236f, -0.70710678119f, -0.92387953251f};
    const float WS[8] = {0.f, 0.38268343236f, 0.70710678119f, 0.92387953251f,
                         1.f, 0.92387953251f, 0.70710678119f, 0.38268343236f};
    #pragma unroll
    for (int stage = 0; stage < 4; ++stage) {
        const int L = 16 >> stage, half = L >> 1, step = 1 << stage;
        #pragma unroll
        for (int base = 0; base < 16; base += L) {
            #pragma unroll
            for (int j = 0; j < half; ++j) {
                float2 u = f[base + j], v = f[base + half + j];
                f[base + j] = make_float2(u.x + v.x, u.y + v.y);
                float dx = u.x - v.x, dy = u.y - v.y;
                const int t = j * step;
                const float wr = WC[t];
                const float wi = (SGN > 0) ? WS[t] : -WS[t];
                f[base + half + j] = make_float2(dx * wr - dy * wi, dx * wi + dy * wr);
            }
        }
    }
    float2 tmp;
    tmp = f[1];  f[1]  = f[8];  f[8]  = tmp;
    tmp = f[2];  f[2]  = f[4];  f[4]  = tmp;
    tmp = f[3];  f[3]  = f[12]; f[12] = tmp;
    tmp = f[5];  f[5]  = f[10]; f[10] = tmp;
    tmp = f[7];  f[7]  = f[14]; f[14] = tmp;
    tmp = f[11]; f[11] = f[13]; f[13] = tmp;
}

__device__ __forceinline__ float waveReduceSum(float v) {
    #pragma unroll
    for (int off = 32; off > 0; off >>= 1) v += __shfl_down(v, off, 64);
    return v;
}

__device__ __forceinline__ void buildTw(float2* tw, int tid) {
    if (tid < 128) {
        float s, c;
        __sincosf((float)tid * 0.04908738521234052f, &s, &c);   // 2*pi/128
        tw[tid] = make_float2(c, s);
    }
}

// ======== 128-grid sweep phases (R6-R11 proven, TT=512) ========
// Per-axis layout: freq k = ka+8*kb stored at position p = 16*ka+kb.

template<int ES, int LS>
__device__ __forceinline__ void fwdA(float2* __restrict__ F,
                                     const float2* __restrict__ tw, int tid) {
    #pragma unroll
    for (int i = 0; i < 4; ++i) {
        int u = i * TT + tid;
        int t = u >> 7, x = u & 127;
        float2* M = F + x * LS;
        float2 f[8];
        #pragma unroll
        for (int n1 = 0; n1 < 8; ++n1) f[n1] = M[(t + 16 * n1) * ES];
        fft8<-1>(f);
        #pragma unroll
        for (int ka = 0; ka < 8; ++ka)
            M[(t + 16 * ka) * ES] = cmulc(f[ka], tw[t * ka]);
    }
}

template<int ES, int LS>
__device__ __forceinline__ void fwdB(float2* __restrict__ F, int tid) {
    #pragma unroll
    for (int i = 0; i < 2; ++i) {
        int u = i * TT + tid;
        int ka = u >> 7, x = u & 127;
        float2* M = F + x * LS;
        float2 g[16];
        #pragma unroll
        for (int t = 0; t < 16; ++t) g[t] = M[(16 * ka + t) * ES];
        fft16<-1>(g);
        #pragma unroll
        for (int kb = 0; kb < 16; ++kb) M[(16 * ka + kb) * ES] = g[kb];
    }
}

__device__ __forceinline__ void fwdB_col_capture(const float2* __restrict__ F, int tid,
                                                 float2* __restrict__ uh) {
    #pragma unroll
    for (int i = 0; i < 2; ++i) {
        int u = i * TT + tid;
        int ka = u >> 7, c = u & 127;
        float2 g[16];
        #pragma unroll
        for (int t = 0; t < 16; ++t) g[t] = F[(16 * ka + t) * SS + c];
        fft16<-1>(g);
        #pragma unroll
        for (int kb = 0; kb < 16; ++kb) uh[i * 16 + kb] = g[kb];
    }
}

template<int ES, int LS>
__device__ __forceinline__ void invA(float2* __restrict__ F,
                                     const float2* __restrict__ tw, int tid) {
    #pragma unroll
    for (int i = 0; i < 2; ++i) {
        int u = i * TT + tid;
        int ka = u >> 7, x = u & 127;
        float2* M = F + x * LS;
        float2 g[16];
        #pragma unroll
        for (int kb = 0; kb < 16; ++kb) g[kb] = M[(16 * ka + kb) * ES];
        fft16<1>(g);
        #pragma unroll
        for (int t = 0; t < 16; ++t)
            M[(16 * ka + t) * ES] = cmul(g[t], tw[t * ka]);
    }
}

template<int ES, int LS>
__device__ __forceinline__ void invB(float2* __restrict__ F, int tid) {
    #pragma unroll
    for (int i = 0; i < 4; ++i) {
        int u = i * TT + tid;
        int t = u >> 7, x = u & 127;
        float2* M = F + x * LS;
        float2 f[8];
        #pragma unroll
        for (int ka = 0; ka < 8; ++ka) f[ka] = M[(16 * ka + t) * ES];
        fft8<1>(f);
        #pragma unroll
        for (int nh = 0; nh < 8; ++nh) M[(t + 16 * nh) * ES] = f[nh];
    }
}

// Terminal inverse row stepB + magnitude sum (no store, raw mags).
__device__ __forceinline__ void invB_mag_row(float2* __restrict__ F, int tid, float& acc) {
    #pragma unroll
    for (int i = 0; i < 4; ++i) {
        int u = i * TT + tid;
        int t = u >> 7, x = u & 127;
        float2* M = F + x * SS;
        float2 f[8];
        #pragma unroll
        for (int ka = 0; ka < 8; ++ka) f[ka] = M[16 * ka + t];
        fft8<1>(f);
        #pragma unroll
        for (int nh = 0; nh < 8; ++nh)
            acc += sqrtf(f[nh].x * f[nh].x + f[nh].y * f[nh].y);
    }
}

// FUSED: inverse row stepB -> |.| (raw, acc) -> forward row stepA.  Unit (t,row)
// computes spatial cells {t+16n} and immediately re-consumes them: u1 never
// touches LDS; one write sweep and one barrier saved.  (R12)
__device__ __forceinline__ void invBmag_fwdA_row(float2* __restrict__ F,
                                                 const float2* __restrict__ tw,
                                                 int tid, float& acc) {
    #pragma unroll
    for (int i = 0; i < 4; ++i) {
        int u = i * TT + tid;
        int t = u >> 7, x = u & 127;
        float2* M = F + x * SS;
        float2 f[8];
        #pragma unroll
        for (int ka = 0; ka < 8; ++ka) f[ka] = M[16 * ka + t];
        fft8<1>(f);
        #pragma unroll
        for (int nh = 0; nh < 8; ++nh) {
            float m = sqrtf(f[nh].x * f[nh].x + f[nh].y * f[nh].y);
            acc += m;
            f[nh] = make_float2(m, 0.f);
        }
        fft8<-1>(f);
        #pragma unroll
        for (int ka = 0; ka < 8; ++ka)
            M[t + 16 * ka] = cmulc(f[ka], tw[t * ka]);
    }
}

// ---------- K_pre: fused filter bank + coeff zero + i_hat FFT (one launch) ----
__global__ __attribute__((amdgpu_flat_work_group_size(TT, TT), amdgpu_waves_per_eu(2, 2)))
void k_pre(const float* __restrict__ img,
           float* __restrict__ psi,
           float2* __restrict__ ihat,
           float* __restrict__ coeffs) {
    __shared__ float2 F[NN * SS];
    __shared__ float2 tw[128];
    __shared__ float red[TT / 64];
    int blk = blockIdx.x, tid = threadIdx.x;
    if (blk >= 64) {
        if (blk == 80) {
            for (int i = tid; i < 64 * 11; i += TT)
                if (i % 11 != 0) coeffs[i] = 0.f;
            if (tid == 0) *(unsigned*)(coeffs + 704) = 0u;   // completion counter
            return;
        }
        int f = blk - 64;
        int j = f >> 2, l = f & 3;
        float k0    = 2.35619449019234493f / (float)(1 << j);
        float sigma = 0.8f * (float)(1 << j);
        float s2    = sigma * sigma;
        float theta = 0.78539816339744831f * (float)l;
        float k0x = k0 * cosf(theta);
        float k0y = k0 * sinf(theta);
        float beta = expf(-0.5f * s2 * k0 * k0);
        const float FSTEP = 0.04908738521234052f;
        float* dst = psi + (size_t)f * NPIX;
        for (int i = tid; i < NPIX; i += TT) {
            int pr = i >> 7, pc = i & 127;
            int kr = (pr >> 4) + 8 * (pr & 15);
            int kc = (pc >> 4) + 8 * (pc & 15);
            float fr = (float)(kr < 64 ? kr : kr - 128) * FSTEP;
            float fc = (float)(kc < 64 ? kc : kc - 128) * FSTEP;
            float dx = fr - k0x, dy = fc - k0y;
            float g1 = expf(-0.5f * s2 * (dx * dx + dy * dy));
            float g0 = expf(-0.5f * s2 * (fr * fr + fc * fc));
            dst[i] = g1 - beta * g0;
        }
        return;
    }
    // ---- i_hat path ----
    int b = blk;
    buildTw(tw, tid);
    const float* im = img + (size_t)b * NPIX;
    float acc = 0.f;
    #pragma unroll
    for (int k = 0; k < EPT; ++k) {
        int e = k * TT + tid;
        float v = im[e];
        acc += v;
        F[(e >> 7) * SS + (e & 127)] = make_float2(v, 0.f);
    }
    float ws = waveReduceSum(acc);
    if ((tid & 63) == 0) red[tid >> 6] = ws;
    __syncthreads();                             // covers F writes + tw + red
    if (tid == 0) {
        float t = 0.f;
        #pragma unroll
        for (int w = 0; w < TT / 64; ++w) t += red[w];
        coeffs[b * 11 + 0] = t * (1.f / 16384.f);
    }
    fwdA<1, SS>(F, tw, tid);  __syncthreads();
    fwdB<1, SS>(F, tid);      __syncthreads();
    fwdA<SS, 1>(F, tw, tid);  __syncthreads();
    float2 uh[32];
    fwdB_col_capture(F, tid, uh);
    float2* dst = ihat + (size_t)b * NPIX;
    #pragma unroll
    for (int i = 0; i < 2; ++i) {
        int u = i * TT + tid;
        int ka = u >> 7, c = u & 127;
        #pragma unroll
        for (int kb = 0; kb < 16; ++kb)
            dst[(16 * ka + kb) * NN + c] = uh[i * 16 + kb];
    }
}

// ---------- K_scatter (MLP folded in via completion counter) ----------
__global__ __attribute__((amdgpu_flat_work_group_size(TT, TT), amdgpu_waves_per_eu(2, 2)))
void k_scatter(const float2* __restrict__ ihat,
               const float* __restrict__ psi,
               float* __restrict__ coeffs,
               const float* __restrict__ w1, const float* __restrict__ b1,
               const float* __restrict__ w2, const float* __restrict__ b2,
               float* __restrict__ out) {
    __shared__ __align__(16) float2 F[NN * SS];
    __shared__ float2 tw[128];
    __shared__ unsigned lastFlag;
    // Aliased sub-buffers (F dead when used):
    //  G2 = float2[64*SG], G4 = float4[64*SG], H = float2[64*64] = F[8320..)
    float2* G2 = F;
    float4* G4 = (float4*)F;
    float2* H  = F + 8320;
    int tid = threadIdx.x;
    int x = blockIdx.x;
    int b = x & 63, l1 = (x >> 6) & 3, j1 = x >> 8;
    const float2* ih = ihat + (size_t)b * NPIX;
    const float*  p1 = psi + (size_t)(j1 * 4 + l1) * NPIX;
    buildTw(tw, tid);

    // Raw-magnitude normalization constants (u1 scaling folded in):
    const float S1_128 = 9.3132257461547852e-10f;   // 2^-30: s1, 128-grid path
    const float S1_64  = 3.7252902984619141e-9f;    // 2^-28: s1, 64-grid path
    const float S2FULL = 1.4210854715202004e-14f;   // 2^-46: j2=1 full iterations
    const float S2TR   = 5.6843418860808015e-14f;   // 2^-44: j1<=1 trunc
    const float S2TR2  = 2.2737367544323206e-13f;   // 2^-42: j1=2 trunc

    if (j1 >= 2) {
        // =========== 64-grid first order (psi_{j1>=2} fits the +-32 box) ===========
        int kalo = tid >> 7, c = tid & 127;
        int m = c & 15;
        bool colKeep = (m < 4) || (m >= 12);
        int pc64 = 8 * (c >> 4) + ((m < 4) ? m : (m - 8));
        if (colKeep) {
            #pragma unroll
            for (int i = 0; i < 2; ++i) {
                int ka = kalo + 4 * i;
                #pragma unroll
                for (int kb = 0; kb < 16; ++kb) {
                    if (kb < 4 || kb >= 12) {
                        int e = (16 * ka + kb) * NN + c;
                        float2 z = ih[e];
                        float  p = p1[e];
                        int pr64 = 8 * ka + ((kb < 4) ? kb : (kb - 8));
                        G2[pr64 * SG + pc64] = make_float2(z.x * p, z.y * p);
                    }
                }
            }
        }
        __syncthreads();
        {   // col stepA (inverse)
            int col = tid & 63, k8 = tid >> 6;
            float2 f[8];
            #pragma unroll
            for (int kb = 0; kb < 8; ++kb) f[kb] = G2[(8 * k8 + kb) * SG + col];
            fft8<1>(f);
            #pragma unroll
            for (int q = 0; q < 8; ++q)
                G2[(8 * k8 + q) * SG + col] = cmul(f[q], tw[2 * q * k8]);
        }
        __syncthreads();
        {   // col stepB
            int col = tid & 63, q = tid >> 6;
            float2 f[8];
            #pragma unroll
            for (int k8 = 0; k8 < 8; ++k8) f[k8] = G2[(8 * k8 + q) * SG + col];
            fft8<1>(f);
            #pragma unroll
            for (int n1 = 0; n1 < 8; ++n1) G2[(8 * n1 + q) * SG + col] = f[n1];
        }
        __syncthreads();
        {   // row stepA (inverse)
            int row = tid & 63, k8 = tid >> 6;
            float2* R = G2 + row * SG + 8 * k8;
            float2 f[8];
            #pragma unroll
            for (int kb = 0; kb < 8; ++kb) f[kb] = R[kb];
            fft8<1>(f);
            #pragma unroll
            for (int q = 0; q < 8; ++q) R[q] = cmul(f[q], tw[2 * q * k8]);
        }
        __syncthreads();
        float acc = 0.f;
        if (j1 == 3) {
            // terminal: row stepB + mag only
            int row = tid & 63, q = tid >> 6;
            float2* R = G2 + row * SG + q;
            float2 f[8];
            #pragma unroll
            for (int k8 = 0; k8 < 8; ++k8) f[k8] = R[8 * k8];
            fft8<1>(f);
            #pragma unroll
            for (int n1 = 0; n1 < 8; ++n1)
                acc += sqrtf(f[n1].x * f[n1].x + f[n1].y * f[n1].y);
            float ws1 = waveReduceSum(acc);
            if ((tid & 63) == 0) atomicAdd(&coeffs[b * 11 + 1 + j1], ws1 * S1_64);
        } else {
            // FUSED64: row stepB inv -> |.| (raw) -> row stepA fwd (same cells)
            int row = tid & 63, q = tid >> 6;
            float2* R = G2 + row * SG + q;
            float2 f[8];
            #pragma unroll
            for (int k8 = 0; k8 < 8; ++k8) f[k8] = R[8 * k8];
            fft8<1>(f);
            #pragma unroll
            for (int n1 = 0; n1 < 8; ++n1) {
                float mg = sqrtf(f[n1].x * f[n1].x + f[n1].y * f[n1].y);
                acc += mg;
                f[n1] = make_float2(mg, 0.f);
            }
            fft8<-1>(f);
            #pragma unroll
            for (int ka = 0; ka < 8; ++ka)
                R[8 * ka] = cmulc(f[ka], tw[2 * q * ka]);
            float ws1 = waveReduceSum(acc);
            if ((tid & 63) == 0) atomicAdd(&coeffs[b * 11 + 1 + j1], ws1 * S1_64);
            __syncthreads();
            {   // row stepB (forward)
                int row2 = tid & 63, ka = tid >> 6;
                float2* R2 = G2 + row2 * SG + 8 * ka;
                float2 g[8];
                #pragma unroll
                for (int t = 0; t < 8; ++t) g[t] = R2[t];
                fft8<-1>(g);
                #pragma unroll
                for (int kb = 0; kb < 8; ++kb) R2[kb] = g[kb];
            }
            __syncthreads();
            {   // col stepA (forward)
                int col = tid & 63, t = tid >> 6;
                float2 g[8];
                #pragma unroll
                for (int n1 = 0; n1 < 8; ++n1) g[n1] = G2[(t + 8 * n1) * SG + col];
                fft8<-1>(g);
                #pragma unroll
                for (int ka = 0; ka < 8; ++ka)
                    G2[(t + 8 * ka) * SG + col] = cmulc(g[ka], tw[2 * t * ka]);
            }
            __syncthreads();
            {   // col stepB (forward) -> H (perm64 freq layout)
                int col = tid & 63, ka = tid >> 6;
                float2 g[8];
                #pragma unroll
                for (int t = 0; t < 8; ++t) g[t] = G2[(8 * ka + t) * SG + col];
                fft8<-1>(g);
                #pragma unroll
                for (int kb = 0; kb < 8; ++kb) H[(8 * ka + kb) * 64 + col] = g[kb];
            }
            __syncthreads();

            // ---- truncated second order, j2 = 3, two filters per sweep set ----
            for (int half = 0; half < 2; ++half) {
                const float* p2a = psi + (size_t)(12 + 2 * half) * NPIX;
                const float* p2b = p2a + NPIX;
                if (colKeep) {
                    #pragma unroll
                    for (int i = 0; i < 2; ++i) {
                        int ka = kalo + 4 * i;
                        #pragma unroll
                        for (int kb = 0; kb < 16; ++kb) {
                            if (kb < 4 || kb >= 12) {
                                int pr64 = 8 * ka + ((kb < 4) ? kb : (kb - 8));
                                float2 z = H[pr64 * 64 + pc64];
                                int e = (16 * ka + kb) * NN + c;
                                float pa = p2a[e], pb = p2b[e];
                                G4[pr64 * SG + pc64] =
                                    make_float4(z.x * pa, z.y * pa, z.x * pb, z.y * pb);
                            }
                        }
                    }
                }
                __syncthreads();
                {   // col stepA
                    int col = tid & 63, k8 = tid >> 6;
                    float2 f0[8], f1[8];
                    #pragma unroll
                    for (int kb = 0; kb < 8; ++kb) {
                        float4 v = G4[(8 * k8 + kb) * SG + col];
                        f0[kb] = make_float2(v.x, v.y); f1[kb] = make_float2(v.z, v.w);
                    }
                    fft8<1>(f0); fft8<1>(f1);
                    #pragma unroll
                    for (int q = 0; q < 8; ++q) {
                        float2 w = tw[2 * q * k8];
                        float2 a = cmul(f0[q], w), d = cmul(f1[q], w);
                        G4[(8 * k8 + q) * SG + col] = make_float4(a.x, a.y, d.x, d.y);
                    }
                }
                __syncthreads();
                {   // col stepB
                    int col = tid & 63, q = tid >> 6;
                    float2 f0[8], f1[8];
                    #pragma unroll
                    for (int k8 = 0; k8 < 8; ++k8) {
                        float4 v = G4[(8 * k8 + q) * SG + col];
                        f0[k8] = make_float2(v.x, v.y); f1[k8] = make_float2(v.z, v.w);
                    }
                    fft8<1>(f0); fft8<1>(f1);
                    #pragma unroll
                    for (int n1 = 0; n1 < 8; ++n1)
                        G4[(8 * n1 + q) * SG + col] =
                            make_float4(f0[n1].x, f0[n1].y, f1[n1].x, f1[n1].y);
                }
                __syncthreads();
                {   // row stepA
                    int row = tid & 63, k8 = tid >> 6;
                    float4* R = G4 + row * SG + 8 * k8;
                    float2 f0[8], f1[8];
                    #pragma unroll
                    for (int kb = 0; kb < 8; ++kb) {
                        float4 v = R[kb];
                        f0[kb] = make_float2(v.x, v.y); f1[kb] = make_float2(v.z, v.w);
                    }
                    fft8<1>(f0); fft8<1>(f1);
                    #pragma unroll
                    for (int q = 0; q < 8; ++q) {
                        float2 w = tw[2 * q * k8];
                        float2 a = cmul(f0[q], w), d = cmul(f1[q], w);
                        R[q] = make_float4(a.x, a.y, d.x, d.y);
                    }
                }
                __syncthreads();
                float a2 = 0.f;
                {   // row stepB + mag
                    int row = tid & 63, q = tid >> 6;
                    float4* R = G4 + row * SG + q;
                    float2 f0[8], f1[8];
                    #pragma unroll
                    for (int k8 = 0; k8 < 8; ++k8) {
                        float4 v = R[8 * k8];
                        f0[k8] = make_float2(v.x, v.y); f1[k8] = make_float2(v.z, v.w);
                    }
                    fft8<1>(f0); fft8<1>(f1);
                    #pragma unroll
                    for (int n1 = 0; n1 < 8; ++n1) {
                        a2 += sqrtf(f0[n1].x * f0[n1].x + f0[n1].y * f0[n1].y);
                        a2 += sqrtf(f1[n1].x * f1[n1].x + f1[n1].y * f1[n1].y);
                    }
                }
                float ws2 = waveReduceSum(a2);
                if ((tid & 63) == 0) atomicAdd(&coeffs[b * 11 + 5 + 5], ws2 * S2TR2);
                __syncthreads();
            }
        }
    } else {
        // ================= j1 <= 1: full 128-grid path =================
        int kalo = tid >> 7, c = tid & 127;
        {
            #pragma unroll
            for (int i = 0; i < 2; ++i) {
                int ka = kalo + 4 * i;
                float2 g[16];
                #pragma unroll
                for (int kb = 0; kb < 16; ++kb) {
                    int e = (16 * ka + kb) * NN + c;
                    float2 z = ih[e];
                    float  p = p1[e];
                    g[kb] = make_float2(z.x * p, z.y * p);
                }
                fft16<1>(g);
                #pragma unroll
                for (int t = 0; t < 16; ++t)
                    F[(16 * ka + t) * SS + c] = cmul(g[t], tw[t * ka]);
            }
        }
        __syncthreads();
        invB<SS, 1>(F, tid);      __syncthreads();
        invA<1, SS>(F, tw, tid);  __syncthreads();
        float acc = 0.f;
        invBmag_fwdA_row(F, tw, tid, acc);        // FUSED: |.| + fwd row stepA
        float ws1 = waveReduceSum(acc);
        if ((tid & 63) == 0) atomicAdd(&coeffs[b * 11 + 1 + j1], ws1 * S1_128);
        __syncthreads();
        fwdB<1, SS>(F, tid);      __syncthreads();
        fwdA<SS, 1>(F, tw, tid);  __syncthreads();
        float2 uh[32];
        fwdB_col_capture(F, tid, uh);

        int m = c & 15;
        bool colKeep = (m < 4) || (m >= 12);
        int pc64 = 8 * (c >> 4) + ((m < 4) ? m : (m - 8));

        if (j1 == 0) {
            for (int it = 0; it < 4; ++it) {
                const float* p2 = psi + (size_t)(4 + it) * NPIX;
                #pragma unroll
                for (int i = 0; i < 2; ++i) {
                    int ka = kalo + 4 * i;
                    float2 g[16];
                    #pragma unroll
                    for (int kb = 0; kb < 16; ++kb) {
                        float p = p2[(16 * ka + kb) * NN + c];
                        float2 z = uh[i * 16 + kb];
                        g[kb] = make_float2(z.x * p, z.y * p);
                    }
                    fft16<1>(g);
                    #pragma unroll
                    for (int t = 0; t < 16; ++t)
                        F[(16 * ka + t) * SS + c] = cmul(g[t], tw[t * ka]);
                }
                __syncthreads();
                invB<SS, 1>(F, tid);      __syncthreads();
                invA<1, SS>(F, tw, tid);  __syncthreads();
                float a2 = 0.f;
                invB_mag_row(F, tid, a2);
                float ws2 = waveReduceSum(a2);
                if ((tid & 63) == 0) atomicAdd(&coeffs[b * 11 + 5 + 0], ws2 * S2FULL);
                __syncthreads();
            }
        } else {
            __syncthreads();
        }

        if (colKeep) {
            #pragma unroll
            for (int i = 0; i < 2; ++i) {
                int ka = kalo + 4 * i;
                #pragma unroll
                for (int kb = 0; kb < 16; ++kb) {
                    if (kb < 4 || kb >= 12) {
                        int pr64 = 8 * ka + ((kb < 4) ? kb : (kb - 8));
                        H[pr64 * 64 + pc64] = uh[i * 16 + kb];
                    }
                }
            }
        }
        __syncthreads();

        for (int j2 = 2; j2 <= 3; ++j2) {
            int pair = (j1 == 0) ? (j2 - 1) : (j2 + 1);
            for (int half = 0; half < 2; ++half) {
                const float* p2a = psi + (size_t)(j2 * 4 + 2 * half) * NPIX;
                const float* p2b = p2a + NPIX;
                if (colKeep) {
                    #pragma unroll
                    for (int i = 0; i < 2; ++i) {
                        int ka = kalo + 4 * i;
                        #pragma unroll
                        for (int kb = 0; kb < 16; ++kb) {
                            if (kb < 4 || kb >= 12) {
                                int pr64 = 8 * ka + ((kb < 4) ? kb : (kb - 8));
                                float2 z = H[pr64 * 64 + pc64];
                                int e = (16 * ka + kb) * NN + c;
                                float pa = p2a[e], pb = p2b[e];
                                G4[pr64 * SG + pc64] =
                                    make_float4(z.x * pa, z.y * pa, z.x * pb, z.y * pb);
                            }
                        }
                    }
                }
                __syncthreads();
                {   // col stepA
                    int col = tid & 63, k8 = tid >> 6;
                    float2 f0[8], f1[8];
                    #pragma unroll
                    for (int kb = 0; kb < 8; ++kb) {
                        float4 v = G4[(8 * k8 + kb) * SG + col];
                        f0[kb] = make_float2(v.x, v.y); f1[kb] = make_float2(v.z, v.w);
                    }
                    fft8<1>(f0); fft8<1>(f1);
                    #pragma unroll
                    for (int q = 0; q < 8; ++q) {
                        float2 w = tw[2 * q * k8];
                        float2 a = cmul(f0[q], w), d = cmul(f1[q], w);
                        G4[(8 * k8 + q) * SG + col] = make_float4(a.x, a.y, d.x, d.y);
                    }
                }
                __syncthreads();
                {   // col stepB
                    int col = tid & 63, q = tid >> 6;
                    float2 f0[8], f1[8];
                    #pragma unroll
                    for (int k8 = 0; k8 < 8; ++k8) {
                        float4 v = G4[(8 * k8 + q) * SG + col];
                        f0[k8] = make_float2(v.x, v.y); f1[k8] = make_float2(v.z, v.w);
                    }
                    fft8<1>(f0); fft8<1>(f1);
                    #pragma unroll
                    for (int n1 = 0; n1 < 8; ++n1)
                        G4[(8 * n1 + q) * SG + col] =
                            make_float4(f0[n1].x, f0[n1].y, f1[n1].x, f1[n1].y);
                }
                __syncthreads();
                {   // row stepA
                    int row = tid & 63, k8 = tid >> 6;
                    float4* R = G4 + row * SG + 8 * k8;
                    float2 f0[8], f1[8];
                    #pragma unroll
                    for (int kb = 0; kb < 8; ++kb) {
                        float4 v = R[kb];
                        f0[kb] = make_float2(v.x, v.y); f1[kb] = make_float2(v.z, v.w);
                    }
                    fft8<1>(f0); fft8<1>(f1);
                    #pragma unroll
                    for (int q = 0; q < 8; ++q) {
                        float2 w = tw[2 * q * k8];
                        float2 a = cmul(f0[q], w), d = cmul(f1[q], w);
                        R[q] = make_float4(a.x, a.y, d.x, d.y);
                    }
                }
                __syncthreads();
                float a2 = 0.f;
                {   // row stepB + mag
                    int row = tid & 63, q = tid >> 6;
                    float4* R = G4 + row * SG + q;
                    float2 f0[8], f1[8];
                    #pragma unroll
                    for (int k8 = 0; k8 < 8; ++k8) {
                        float4 v = R[8 * k8];
                        f0[k8] = make_float2(v.x, v.y); f1[k8] = make_float2(v.z, v.w);
                    }
                    fft8<1>(f0); fft8<1>(f1);
                    #pragma unroll
                    for (int n1 = 0; n1 < 8; ++n1) {
                        a2 += sqrtf(f0[n1].x * f0[n1].x + f0[n1].y * f0[n1].y);
                        a2 += sqrtf(f1[n1].x * f1[n1].x + f1[n1].y * f1[n1].y);
                    }
                }
                float ws2 = waveReduceSum(a2);
                if ((tid & 63) == 0) atomicAdd(&coeffs[b * 11 + 5 + pair], ws2 * S2TR);
                __syncthreads();
            }
        }
    }

    // ====== completion counter: last block runs the MLP head ======
    __threadfence();                              // coeff atomics visible device-wide
    if (tid == 0) {
        unsigned old = atomicAdd((unsigned*)(coeffs + 704), 1u);
        lastFlag = (old == 1023u) ? 1u : 0u;
    }
    __syncthreads();
    if (lastFlag && tid < 64) {
        int bb = tid;
        float cc[11];
        #pragma unroll
        for (int i = 0; i < 11; ++i)
            cc[i] = atomicAdd(&coeffs[bb * 11 + i], 0.f);   // device-coherent load
        float h[4];
        #pragma unroll
        for (int k = 0; k < 4; ++k) {
            float s = b1[k];
            #pragma unroll
            for (int i = 0; i < 11; ++i) s += w1[k * 11 + i] * cc[i];
            h[k] = fmaxf(s, 0.f);
        }
        #pragma unroll
        for (int o = 0; o < 10; ++o) {
            float s = b2[o];
            #pragma unroll
            for (int k = 0; k < 4; ++k) s += w2[o * 4 + k] * h[k];
            out[bb * 10 + o] = 1.f / (1.f + expf(-s));
        }
    }
}

extern "C" void kernel_launch(void* const* d_in, const int* in_sizes, int n_in,
                              void* d_out, int out_size, void* d_ws, size_t ws_size,
                              hipStream_t stream) {
    const float* img = (const float*)d_in[0];
    const float* w1  = (const float*)d_in[1];
    const float* b1  = (const float*)d_in[2];
    const float* w2  = (const float*)d_in[3];
    const float* b2  = (const float*)d_in[4];
    float* out = (float*)d_out;

    // workspace layout (floats): psi[16*16384] | ihat[64*16384 float2] |
    //                            coeffs[64*11] | counter[1]
    float*  ws     = (float*)d_ws;
    float*  psi    = ws;
    float2* ihat   = (float2*)(ws + 16 * NPIX);
    float*  coeffs = ws + 16 * NPIX + 2 * 64 * NPIX;

    hipLaunchKernelGGL(k_pre,     dim3(81),   dim3(TT), 0, stream, img, psi, ihat, coeffs);
    hipLaunchKernelGGL(k_scatter, dim3(1024), dim3(TT), 0, stream, ihat, psi, coeffs,
                       w1, b1, w2, b2, out);
}

// Round 13
// 251.680 us; speedup vs baseline: 1.4409x; 1.4409x over previous
//
#include <hip/hip_runtime.h>
#include <math.h>

#define NN   128
#define SS   129          // LDS row stride in float2 (ODD -> conflict-free lane stride)
#define TT   512          // PROVEN: TT=512 allocates ~112-128 VGPR no-spill (R4/R6-R9);
                          // TT=1024 ALWAYS gets 64 VGPR + spill (R2/R3/R10). Never 1024.
#define NPIX 16384        // 128*128
#define EPT  32           // NPIX / TT
#define SG   65           // 64-grid row stride (float2 or float4 units)

// R12 lesson: NO __threadfence() tail / in-kernel MLP fold -- 512 threads x 1024
// blocks of device-scope fences cost ~115 us.  Separate tiny k_mlp launch wins.

__device__ __forceinline__ float2 cmul(float2 a, float2 w) {
    return make_float2(a.x * w.x - a.y * w.y, a.x * w.y + a.y * w.x);
}
__device__ __forceinline__ float2 cmulc(float2 a, float2 w) {   // a * conj(w)
    return make_float2(a.x * w.x + a.y * w.y, a.y * w.x - a.x * w.y);
}

// ---------- register FFT codelets (verified R2-R12) ----------
template<int SGN>
__device__ __forceinline__ void fft8(float2* f) {
    const float R = 0.70710678118654752f;
    const float WC[4] = {1.f, R, 0.f, -R};
    const float WS[4] = {0.f, R, 1.f, R};
    #pragma unroll
    for (int stage = 0; stage < 3; ++stage) {
        const int L = 8 >> stage, half = L >> 1, step = 1 << stage;
        #pragma unroll
        for (int base = 0; base < 8; base += L) {
            #pragma unroll
            for (int j = 0; j < half; ++j) {
                float2 u = f[base + j], v = f[base + half + j];
                f[base + j] = make_float2(u.x + v.x, u.y + v.y);
                float dx = u.x - v.x, dy = u.y - v.y;
                const int t = j * step;
                const float wr = WC[t];
                const float wi = (SGN > 0) ? WS[t] : -WS[t];
                f[base + half + j] = make_float2(dx * wr - dy * wi, dx * wi + dy * wr);
            }
        }
    }
    float2 tmp;
    tmp = f[1]; f[1] = f[4]; f[4] = tmp;
    tmp = f[3]; f[3] = f[6]; f[6] = tmp;
}

template<int SGN>
__device__ __forceinline__ void fft16(float2* f) {
    const float WC[8] = {1.f, 0.92387953251f, 0.70710678119f, 0.38268343236f,
                         0.f, -0.38268343236f, -0.70710678119f, -0.92387953251f};
    const float WS[8] = {0.f, 0.38268343236f, 0.70710678119f, 0.92387953251f,
                         1.f, 0.92387953251f, 0.70710678119f, 0.38268343236f};
    #pragma unroll
    for (int stage = 0; stage < 4; ++stage) {
        const int L = 16 >> stage, half = L >> 1, step = 1 << stage;
        #pragma unroll
        for (int base = 0; base < 16; base += L) {
            #pragma unroll
            for (int j = 0; j < half; ++j) {
                float2 u = f[base + j], v = f[base + half + j];
                f[base + j] = make_float2(u.x + v.x, u.y + v.y);
                float dx = u.x - v.x, dy = u.y - v.y;
                const int t = j * step;
                const float wr = WC[t];
                const float wi = (SGN > 0) ? WS[t] : -WS[t];
                f[base + half + j] = make_float2(dx * wr - dy * wi, dx * wi + dy * wr);
            }
        }
    }
    float2 tmp;
    tmp = f[1];  f[1]  = f[8];  f[8]  = tmp;
    tmp = f[2];  f[2]  = f[4];  f[4]  = tmp;
    tmp = f[3];  f[3]  = f[12]; f[12] = tmp;
    tmp = f[5];  f[5]  = f[10]; f[10] = tmp;
    tmp = f[7];  f[7]  = f[14]; f[14] = tmp;
    tmp = f[11]; f[11] = f[13]; f[13] = tmp;
}

__device__ __forceinline__ float waveReduceSum(float v) {
    #pragma unroll
    for (int off = 32; off > 0; off >>= 1) v += __shfl_down(v, off, 64);
    return v;
}

__device__ __forceinline__ void buildTw(float2* tw, int tid) {
    if (tid < 128) {
        float s, c;
        __sincosf((float)tid * 0.04908738521234052f, &s, &c);   // 2*pi/128
        tw[tid] = make_float2(c, s);
    }
}

// ======== 128-grid sweep phases (R6-R12 proven, TT=512) ========
// Per-axis layout: freq k = ka+8*kb stored at position p = 16*ka+kb.

template<int ES, int LS>
__device__ __forceinline__ void fwdA(float2* __restrict__ F,
                                     const float2* __restrict__ tw, int tid) {
    #pragma unroll
    for (int i = 0; i < 4; ++i) {
        int u = i * TT + tid;
        int t = u >> 7, x = u & 127;
        float2* M = F + x * LS;
        float2 f[8];
        #pragma unroll
        for (int n1 = 0; n1 < 8; ++n1) f[n1] = M[(t + 16 * n1) * ES];
        fft8<-1>(f);
        #pragma unroll
        for (int ka = 0; ka < 8; ++ka)
            M[(t + 16 * ka) * ES] = cmulc(f[ka], tw[t * ka]);
    }
}

template<int ES, int LS>
__device__ __forceinline__ void fwdB(float2* __restrict__ F, int tid) {
    #pragma unroll
    for (int i = 0; i < 2; ++i) {
        int u = i * TT + tid;
        int ka = u >> 7, x = u & 127;
        float2* M = F + x * LS;
        float2 g[16];
        #pragma unroll
        for (int t = 0; t < 16; ++t) g[t] = M[(16 * ka + t) * ES];
        fft16<-1>(g);
        #pragma unroll
        for (int kb = 0; kb < 16; ++kb) M[(16 * ka + kb) * ES] = g[kb];
    }
}

__device__ __forceinline__ void fwdB_col_capture(const float2* __restrict__ F, int tid,
                                                 float2* __restrict__ uh) {
    #pragma unroll
    for (int i = 0; i < 2; ++i) {
        int u = i * TT + tid;
        int ka = u >> 7, c = u & 127;
        float2 g[16];
        #pragma unroll
        for (int t = 0; t < 16; ++t) g[t] = F[(16 * ka + t) * SS + c];
        fft16<-1>(g);
        #pragma unroll
        for (int kb = 0; kb < 16; ++kb) uh[i * 16 + kb] = g[kb];
    }
}

template<int ES, int LS>
__device__ __forceinline__ void invA(float2* __restrict__ F,
                                     const float2* __restrict__ tw, int tid) {
    #pragma unroll
    for (int i = 0; i < 2; ++i) {
        int u = i * TT + tid;
        int ka = u >> 7, x = u & 127;
        float2* M = F + x * LS;
        float2 g[16];
        #pragma unroll
        for (int kb = 0; kb < 16; ++kb) g[kb] = M[(16 * ka + kb) * ES];
        fft16<1>(g);
        #pragma unroll
        for (int t = 0; t < 16; ++t)
            M[(16 * ka + t) * ES] = cmul(g[t], tw[t * ka]);
    }
}

template<int ES, int LS>
__device__ __forceinline__ void invB(float2* __restrict__ F, int tid) {
    #pragma unroll
    for (int i = 0; i < 4; ++i) {
        int u = i * TT + tid;
        int t = u >> 7, x = u & 127;
        float2* M = F + x * LS;
        float2 f[8];
        #pragma unroll
        for (int ka = 0; ka < 8; ++ka) f[ka] = M[(16 * ka + t) * ES];
        fft8<1>(f);
        #pragma unroll
        for (int nh = 0; nh < 8; ++nh) M[(t + 16 * nh) * ES] = f[nh];
    }
}

// Terminal inverse row stepB + magnitude sum (no store, raw mags).
__device__ __forceinline__ void invB_mag_row(float2* __restrict__ F, int tid, float& acc) {
    #pragma unroll
    for (int i = 0; i < 4; ++i) {
        int u = i * TT + tid;
        int t = u >> 7, x = u & 127;
        float2* M = F + x * SS;
        float2 f[8];
        #pragma unroll
        for (int ka = 0; ka < 8; ++ka) f[ka] = M[16 * ka + t];
        fft8<1>(f);
        #pragma unroll
        for (int nh = 0; nh < 8; ++nh)
            acc += sqrtf(f[nh].x * f[nh].x + f[nh].y * f[nh].y);
    }
}

// FUSED: inverse row stepB -> |.| (raw, acc) -> forward row stepA.  Unit (t,row)
// computes spatial cells {t+16n} and immediately re-consumes them: u1 never
// touches LDS; one write sweep and one barrier saved.  (R12, kept in R13)
__device__ __forceinline__ void invBmag_fwdA_row(float2* __restrict__ F,
                                                 const float2* __restrict__ tw,
                                                 int tid, float& acc) {
    #pragma unroll
    for (int i = 0; i < 4; ++i) {
        int u = i * TT + tid;
        int t = u >> 7, x = u & 127;
        float2* M = F + x * SS;
        float2 f[8];
        #pragma unroll
        for (int ka = 0; ka < 8; ++ka) f[ka] = M[16 * ka + t];
        fft8<1>(f);
        #pragma unroll
        for (int nh = 0; nh < 8; ++nh) {
            float m = sqrtf(f[nh].x * f[nh].x + f[nh].y * f[nh].y);
            acc += m;
            f[nh] = make_float2(m, 0.f);
        }
        fft8<-1>(f);
        #pragma unroll
        for (int ka = 0; ka < 8; ++ka)
            M[t + 16 * ka] = cmulc(f[ka], tw[t * ka]);
    }
}

// ---------- K_pre: fused filter bank + coeff zero + i_hat FFT (one launch) ----
__global__ __attribute__((amdgpu_flat_work_group_size(TT, TT), amdgpu_waves_per_eu(2, 2)))
void k_pre(const float* __restrict__ img,
           float* __restrict__ psi,
           float2* __restrict__ ihat,
           float* __restrict__ coeffs) {
    __shared__ float2 F[NN * SS];
    __shared__ float2 tw[128];
    __shared__ float red[TT / 64];
    int blk = blockIdx.x, tid = threadIdx.x;
    if (blk >= 64) {
        if (blk == 80) {
            for (int i = tid; i < 64 * 11; i += TT)
                if (i % 11 != 0) coeffs[i] = 0.f;
            return;
        }
        int f = blk - 64;
        int j = f >> 2, l = f & 3;
        float k0    = 2.35619449019234493f / (float)(1 << j);
        float sigma = 0.8f * (float)(1 << j);
        float s2    = sigma * sigma;
        float theta = 0.78539816339744831f * (float)l;
        float k0x = k0 * cosf(theta);
        float k0y = k0 * sinf(theta);
        float beta = expf(-0.5f * s2 * k0 * k0);
        const float FSTEP = 0.04908738521234052f;
        float* dst = psi + (size_t)f * NPIX;
        for (int i = tid; i < NPIX; i += TT) {
            int pr = i >> 7, pc = i & 127;
            int kr = (pr >> 4) + 8 * (pr & 15);
            int kc = (pc >> 4) + 8 * (pc & 15);
            float fr = (float)(kr < 64 ? kr : kr - 128) * FSTEP;
            float fc = (float)(kc < 64 ? kc : kc - 128) * FSTEP;
            float dx = fr - k0x, dy = fc - k0y;
            float g1 = expf(-0.5f * s2 * (dx * dx + dy * dy));
            float g0 = expf(-0.5f * s2 * (fr * fr + fc * fc));
            dst[i] = g1 - beta * g0;
        }
        return;
    }
    // ---- i_hat path ----
    int b = blk;
    buildTw(tw, tid);
    const float* im = img + (size_t)b * NPIX;
    float acc = 0.f;
    #pragma unroll
    for (int k = 0; k < EPT; ++k) {
        int e = k * TT + tid;
        float v = im[e];
        acc += v;
        F[(e >> 7) * SS + (e & 127)] = make_float2(v, 0.f);
    }
    float ws = waveReduceSum(acc);
    if ((tid & 63) == 0) red[tid >> 6] = ws;
    __syncthreads();                             // covers F writes + tw + red
    if (tid == 0) {
        float t = 0.f;
        #pragma unroll
        for (int w = 0; w < TT / 64; ++w) t += red[w];
        coeffs[b * 11 + 0] = t * (1.f / 16384.f);
    }
    fwdA<1, SS>(F, tw, tid);  __syncthreads();
    fwdB<1, SS>(F, tid);      __syncthreads();
    fwdA<SS, 1>(F, tw, tid);  __syncthreads();
    float2 uh[32];
    fwdB_col_capture(F, tid, uh);
    float2* dst = ihat + (size_t)b * NPIX;
    #pragma unroll
    for (int i = 0; i < 2; ++i) {
        int u = i * TT + tid;
        int ka = u >> 7, c = u & 127;
        #pragma unroll
        for (int kb = 0; kb < 16; ++kb)
            dst[(16 * ka + kb) * NN + c] = uh[i * 16 + kb];
    }
}

// ---------- K_scatter ----------
__global__ __attribute__((amdgpu_flat_work_group_size(TT, TT), amdgpu_waves_per_eu(2, 2)))
void k_scatter(const float2* __restrict__ ihat,
               const float* __restrict__ psi,
               float* __restrict__ coeffs) {
    __shared__ __align__(16) float2 F[NN * SS];
    __shared__ float2 tw[128];
    // Aliased sub-buffers (F dead when used):
    //  G2 = float2[64*SG], G4 = float4[64*SG], H = float2[64*64] = F[8320..)
    float2* G2 = F;
    float4* G4 = (float4*)F;
    float2* H  = F + 8320;
    int tid = threadIdx.x;
    int x = blockIdx.x;
    int b = x & 63, l1 = (x >> 6) & 3, j1 = x >> 8;
    const float2* ih = ihat + (size_t)b * NPIX;
    const float*  p1 = psi + (size_t)(j1 * 4 + l1) * NPIX;
    buildTw(tw, tid);

    // Raw-magnitude normalization constants (u1 scaling folded in):
    const float S1_128 = 9.3132257461547852e-10f;   // 2^-30: s1, 128-grid path
    const float S1_64  = 3.7252902984619141e-9f;    // 2^-28: s1, 64-grid path
    const float S2FULL = 1.4210854715202004e-14f;   // 2^-46: j2=1 full iterations
    const float S2TR   = 5.6843418860808015e-14f;   // 2^-44: j1<=1 trunc
    const float S2TR2  = 2.2737367544323206e-13f;   // 2^-42: j1=2 trunc

    if (j1 >= 2) {
        // =========== 64-grid first order (psi_{j1>=2} fits the +-32 box) ===========
        int kalo = tid >> 7, c = tid & 127;
        int m = c & 15;
        bool colKeep = (m < 4) || (m >= 12);
        int pc64 = 8 * (c >> 4) + ((m < 4) ? m : (m - 8));
        if (colKeep) {
            #pragma unroll
            for (int i = 0; i < 2; ++i) {
                int ka = kalo + 4 * i;
                #pragma unroll
                for (int kb = 0; kb < 16; ++kb) {
                    if (kb < 4 || kb >= 12) {
                        int e = (16 * ka + kb) * NN + c;
                        float2 z = ih[e];
                        float  p = p1[e];
                        int pr64 = 8 * ka + ((kb < 4) ? kb : (kb - 8));
                        G2[pr64 * SG + pc64] = make_float2(z.x * p, z.y * p);
                    }
                }
            }
        }
        __syncthreads();
        {   // col stepA (inverse)
            int col = tid & 63, k8 = tid >> 6;
            float2 f[8];
            #pragma unroll
            for (int kb = 0; kb < 8; ++kb) f[kb] = G2[(8 * k8 + kb) * SG + col];
            fft8<1>(f);
            #pragma unroll
            for (int q = 0; q < 8; ++q)
                G2[(8 * k8 + q) * SG + col] = cmul(f[q], tw[2 * q * k8]);
        }
        __syncthreads();
        {   // col stepB
            int col = tid & 63, q = tid >> 6;
            float2 f[8];
            #pragma unroll
            for (int k8 = 0; k8 < 8; ++k8) f[k8] = G2[(8 * k8 + q) * SG + col];
            fft8<1>(f);
            #pragma unroll
            for (int n1 = 0; n1 < 8; ++n1) G2[(8 * n1 + q) * SG + col] = f[n1];
        }
        __syncthreads();
        {   // row stepA (inverse)
            int row = tid & 63, k8 = tid >> 6;
            float2* R = G2 + row * SG + 8 * k8;
            float2 f[8];
            #pragma unroll
            for (int kb = 0; kb < 8; ++kb) f[kb] = R[kb];
            fft8<1>(f);
            #pragma unroll
            for (int q = 0; q < 8; ++q) R[q] = cmul(f[q], tw[2 * q * k8]);
        }
        __syncthreads();
        float acc = 0.f;
        if (j1 == 3) {
            // terminal: row stepB + mag only
            int row = tid & 63, q = tid >> 6;
            float2* R = G2 + row * SG + q;
            float2 f[8];
            #pragma unroll
            for (int k8 = 0; k8 < 8; ++k8) f[k8] = R[8 * k8];
            fft8<1>(f);
            #pragma unroll
            for (int n1 = 0; n1 < 8; ++n1)
                acc += sqrtf(f[n1].x * f[n1].x + f[n1].y * f[n1].y);
            float ws1 = waveReduceSum(acc);
            if ((tid & 63) == 0) atomicAdd(&coeffs[b * 11 + 1 + j1], ws1 * S1_64);
        } else {
            // FUSED64: row stepB inv -> |.| (raw) -> row stepA fwd (same cells)
            int row = tid & 63, q = tid >> 6;
            float2* R = G2 + row * SG + q;
            float2 f[8];
            #pragma unroll
            for (int k8 = 0; k8 < 8; ++k8) f[k8] = R[8 * k8];
            fft8<1>(f);
            #pragma unroll
            for (int n1 = 0; n1 < 8; ++n1) {
                float mg = sqrtf(f[n1].x * f[n1].x + f[n1].y * f[n1].y);
                acc += mg;
                f[n1] = make_float2(mg, 0.f);
            }
            fft8<-1>(f);
            #pragma unroll
            for (int ka = 0; ka < 8; ++ka)
                R[8 * ka] = cmulc(f[ka], tw[2 * q * ka]);
            float ws1 = waveReduceSum(acc);
            if ((tid & 63) == 0) atomicAdd(&coeffs[b * 11 + 1 + j1], ws1 * S1_64);
            __syncthreads();
            {   // row stepB (forward)
                int row2 = tid & 63, ka = tid >> 6;
                float2* R2 = G2 + row2 * SG + 8 * ka;
                float2 g[8];
                #pragma unroll
                for (int t = 0; t < 8; ++t) g[t] = R2[t];
                fft8<-1>(g);
                #pragma unroll
                for (int kb = 0; kb < 8; ++kb) R2[kb] = g[kb];
            }
            __syncthreads();
            {   // col stepA (forward)
                int col = tid & 63, t = tid >> 6;
                float2 g[8];
                #pragma unroll
                for (int n1 = 0; n1 < 8; ++n1) g[n1] = G2[(t + 8 * n1) * SG + col];
                fft8<-1>(g);
                #pragma unroll
                for (int ka = 0; ka < 8; ++ka)
                    G2[(t + 8 * ka) * SG + col] = cmulc(g[ka], tw[2 * t * ka]);
            }
            __syncthreads();
            {   // col stepB (forward) -> H (perm64 freq layout)
                int col = tid & 63, ka = tid >> 6;
                float2 g[8];
                #pragma unroll
                for (int t = 0; t < 8; ++t) g[t] = G2[(8 * ka + t) * SG + col];
                fft8<-1>(g);
                #pragma unroll
                for (int kb = 0; kb < 8; ++kb) H[(8 * ka + kb) * 64 + col] = g[kb];
            }
            __syncthreads();

            // ---- truncated second order, j2 = 3, two filters per sweep set ----
            for (int half = 0; half < 2; ++half) {
                const float* p2a = psi + (size_t)(12 + 2 * half) * NPIX;
                const float* p2b = p2a + NPIX;
                if (colKeep) {
                    #pragma unroll
                    for (int i = 0; i < 2; ++i) {
                        int ka = kalo + 4 * i;
                        #pragma unroll
                        for (int kb = 0; kb < 16; ++kb) {
                            if (kb < 4 || kb >= 12) {
                                int pr64 = 8 * ka + ((kb < 4) ? kb : (kb - 8));
                                float2 z = H[pr64 * 64 + pc64];
                                int e = (16 * ka + kb) * NN + c;
                                float pa = p2a[e], pb = p2b[e];
                                G4[pr64 * SG + pc64] =
                                    make_float4(z.x * pa, z.y * pa, z.x * pb, z.y * pb);
                            }
                        }
                    }
                }
                __syncthreads();
                {   // col stepA
                    int col = tid & 63, k8 = tid >> 6;
                    float2 f0[8], f1[8];
                    #pragma unroll
                    for (int kb = 0; kb < 8; ++kb) {
                        float4 v = G4[(8 * k8 + kb) * SG + col];
                        f0[kb] = make_float2(v.x, v.y); f1[kb] = make_float2(v.z, v.w);
                    }
                    fft8<1>(f0); fft8<1>(f1);
                    #pragma unroll
                    for (int q = 0; q < 8; ++q) {
                        float2 w = tw[2 * q * k8];
                        float2 a = cmul(f0[q], w), d = cmul(f1[q], w);
                        G4[(8 * k8 + q) * SG + col] = make_float4(a.x, a.y, d.x, d.y);
                    }
                }
                __syncthreads();
                {   // col stepB
                    int col = tid & 63, q = tid >> 6;
                    float2 f0[8], f1[8];
                    #pragma unroll
                    for (int k8 = 0; k8 < 8; ++k8) {
                        float4 v = G4[(8 * k8 + q) * SG + col];
                        f0[k8] = make_float2(v.x, v.y); f1[k8] = make_float2(v.z, v.w);
                    }
                    fft8<1>(f0); fft8<1>(f1);
                    #pragma unroll
                    for (int n1 = 0; n1 < 8; ++n1)
                        G4[(8 * n1 + q) * SG + col] =
                            make_float4(f0[n1].x, f0[n1].y, f1[n1].x, f1[n1].y);
                }
                __syncthreads();
                {   // row stepA
                    int row = tid & 63, k8 = tid >> 6;
                    float4* R = G4 + row * SG + 8 * k8;
                    float2 f0[8], f1[8];
                    #pragma unroll
                    for (int kb = 0; kb < 8; ++kb) {
                        float4 v = R[kb];
                        f0[kb] = make_float2(v.x, v.y); f1[kb] = make_float2(v.z, v.w);
                    }
                    fft8<1>(f0); fft8<1>(f1);
                    #pragma unroll
                    for (int q = 0; q < 8; ++q) {
                        float2 w = tw[2 * q * k8];
                        float2 a = cmul(f0[q], w), d = cmul(f1[q], w);
                        R[q] = make_float4(a.x, a.y, d.x, d.y);
                    }
                }
                __syncthreads();
                float a2 = 0.f;
                {   // row stepB + mag
                    int row = tid & 63, q = tid >> 6;
                    float4* R = G4 + row * SG + q;
                    float2 f0[8], f1[8];
                    #pragma unroll
                    for (int k8 = 0; k8 < 8; ++k8) {
                        float4 v = R[8 * k8];
                        f0[k8] = make_float2(v.x, v.y); f1[k8] = make_float2(v.z, v.w);
                    }
                    fft8<1>(f0); fft8<1>(f1);
                    #pragma unroll
                    for (int n1 = 0; n1 < 8; ++n1) {
                        a2 += sqrtf(f0[n1].x * f0[n1].x + f0[n1].y * f0[n1].y);
                        a2 += sqrtf(f1[n1].x * f1[n1].x + f1[n1].y * f1[n1].y);
                    }
                }
                float ws2 = waveReduceSum(a2);
                if ((tid & 63) == 0) atomicAdd(&coeffs[b * 11 + 5 + 5], ws2 * S2TR2);
                __syncthreads();
            }
        }
        return;
    }

    // ================= j1 <= 1: full 128-grid path =================
    int kalo = tid >> 7, c = tid & 127;
    {
        #pragma unroll
        for (int i = 0; i < 2; ++i) {
            int ka = kalo + 4 * i;
            float2 g[16];
            #pragma unroll
            for (int kb = 0; kb < 16; ++kb) {
                int e = (16 * ka + kb) * NN + c;
                float2 z = ih[e];
                float  p = p1[e];
                g[kb] = make_float2(z.x * p, z.y * p);
            }
            fft16<1>(g);
            #pragma unroll
            for (int t = 0; t < 16; ++t)
                F[(16 * ka + t) * SS + c] = cmul(g[t], tw[t * ka]);
        }
    }
    __syncthreads();
    invB<SS, 1>(F, tid);      __syncthreads();
    invA<1, SS>(F, tw, tid);  __syncthreads();
    float acc = 0.f;
    invBmag_fwdA_row(F, tw, tid, acc);        // FUSED: |.| + fwd row stepA
    float ws1 = waveReduceSum(acc);
    if ((tid & 63) == 0) atomicAdd(&coeffs[b * 11 + 1 + j1], ws1 * S1_128);
    __syncthreads();
    fwdB<1, SS>(F, tid);      __syncthreads();
    fwdA<SS, 1>(F, tw, tid);  __syncthreads();
    float2 uh[32];
    fwdB_col_capture(F, tid, uh);

    int m = c & 15;
    bool colKeep = (m < 4) || (m >= 12);
    int pc64 = 8 * (c >> 4) + ((m < 4) ? m : (m - 8));

    if (j1 == 0) {
        for (int it = 0; it < 4; ++it) {
            const float* p2 = psi + (size_t)(4 + it) * NPIX;
            #pragma unroll
            for (int i = 0; i < 2; ++i) {
                int ka = kalo + 4 * i;
                float2 g[16];
                #pragma unroll
                for (int kb = 0; kb < 16; ++kb) {
                    float p = p2[(16 * ka + kb) * NN + c];
                    float2 z = uh[i * 16 + kb];
                    g[kb] = make_float2(z.x * p, z.y * p);
                }
                fft16<1>(g);
                #pragma unroll
                for (int t = 0; t < 16; ++t)
                    F[(16 * ka + t) * SS + c] = cmul(g[t], tw[t * ka]);
            }
            __syncthreads();
            invB<SS, 1>(F, tid);      __syncthreads();
            invA<1, SS>(F, tw, tid);  __syncthreads();
            float a2 = 0.f;
            invB_mag_row(F, tid, a2);
            float ws2 = waveReduceSum(a2);
            if ((tid & 63) == 0) atomicAdd(&coeffs[b * 11 + 5 + 0], ws2 * S2FULL);
            __syncthreads();
        }
    } else {
        __syncthreads();
    }

    if (colKeep) {
        #pragma unroll
        for (int i = 0; i < 2; ++i) {
            int ka = kalo + 4 * i;
            #pragma unroll
            for (int kb = 0; kb < 16; ++kb) {
                if (kb < 4 || kb >= 12) {
                    int pr64 = 8 * ka + ((kb < 4) ? kb : (kb - 8));
                    H[pr64 * 64 + pc64] = uh[i * 16 + kb];
                }
            }
        }
    }
    __syncthreads();

    for (int j2 = 2; j2 <= 3; ++j2) {
        int pair = (j1 == 0) ? (j2 - 1) : (j2 + 1);
        for (int half = 0; half < 2; ++half) {
            const float* p2a = psi + (size_t)(j2 * 4 + 2 * half) * NPIX;
            const float* p2b = p2a + NPIX;
            if (colKeep) {
                #pragma unroll
                for (int i = 0; i < 2; ++i) {
                    int ka = kalo + 4 * i;
                    #pragma unroll
                    for (int kb = 0; kb < 16; ++kb) {
                        if (kb < 4 || kb >= 12) {
                            int pr64 = 8 * ka + ((kb < 4) ? kb : (kb - 8));
                            float2 z = H[pr64 * 64 + pc64];
                            int e = (16 * ka + kb) * NN + c;
                            float pa = p2a[e], pb = p2b[e];
                            G4[pr64 * SG + pc64] =
                                make_float4(z.x * pa, z.y * pa, z.x * pb, z.y * pb);
                        }
                    }
                }
            }
            __syncthreads();
            {   // col stepA
                int col = tid & 63, k8 = tid >> 6;
                float2 f0[8], f1[8];
                #pragma unroll
                for (int kb = 0; kb < 8; ++kb) {
                    float4 v = G4[(8 * k8 + kb) * SG + col];
                    f0[kb] = make_float2(v.x, v.y); f1[kb] = make_float2(v.z, v.w);
                }
                fft8<1>(f0); fft8<1>(f1);
                #pragma unroll
                for (int q = 0; q < 8; ++q) {
                    float2 w = tw[2 * q * k8];
                    float2 a = cmul(f0[q], w), d = cmul(f1[q], w);
                    G4[(8 * k8 + q) * SG + col] = make_float4(a.x, a.y, d.x, d.y);
                }
            }
            __syncthreads();
            {   // col stepB
                int col = tid & 63, q = tid >> 6;
                float2 f0[8], f1[8];
                #pragma unroll
                for (int k8 = 0; k8 < 8; ++k8) {
                    float4 v = G4[(8 * k8 + q) * SG + col];
                    f0[k8] = make_float2(v.x, v.y); f1[k8] = make_float2(v.z, v.w);
                }
                fft8<1>(f0); fft8<1>(f1);
                #pragma unroll
                for (int n1 = 0; n1 < 8; ++n1)
                    G4[(8 * n1 + q) * SG + col] =
                        make_float4(f0[n1].x, f0[n1].y, f1[n1].x, f1[n1].y);
            }
            __syncthreads();
            {   // row stepA
                int row = tid & 63, k8 = tid >> 6;
                float4* R = G4 + row * SG + 8 * k8;
                float2 f0[8], f1[8];
                #pragma unroll
                for (int kb = 0; kb < 8; ++kb) {
                    float4 v = R[kb];
                    f0[kb] = make_float2(v.x, v.y); f1[kb] = make_float2(v.z, v.w);
                }
                fft8<1>(f0); fft8<1>(f1);
                #pragma unroll
                for (int q = 0; q < 8; ++q) {
                    float2 w = tw[2 * q * k8];
                    float2 a = cmul(f0[q], w), d = cmul(f1[q], w);
                    R[q] = make_float4(a.x, a.y, d.x, d.y);
                }
            }
            __syncthreads();
            float a2 = 0.f;
            {   // row stepB + mag
                int row = tid & 63, q = tid >> 6;
                float4* R = G4 + row * SG + q;
                float2 f0[8], f1[8];
                #pragma unroll
                for (int k8 = 0; k8 < 8; ++k8) {
                    float4 v = R[8 * k8];
                    f0[k8] = make_float2(v.x, v.y); f1[k8] = make_float2(v.z, v.w);
                }
                fft8<1>(f0); fft8<1>(f1);
                #pragma unroll
                for (int n1 = 0; n1 < 8; ++n1) {
                    a2 += sqrtf(f0[n1].x * f0[n1].x + f0[n1].y * f0[n1].y);
                    a2 += sqrtf(f1[n1].x * f1[n1].x + f1[n1].y * f1[n1].y);
                }
            }
            float ws2 = waveReduceSum(a2);
            if ((tid & 63) == 0) atomicAdd(&coeffs[b * 11 + 5 + pair], ws2 * S2TR);
            __syncthreads();
        }
    }
}

// ---------- K_mlp: tiny MLP head (separate launch -- see R12 lesson) ----------
__global__ void k_mlp(const float* __restrict__ coeffs,
                      const float* __restrict__ w1, const float* __restrict__ b1,
                      const float* __restrict__ w2, const float* __restrict__ b2,
                      float* __restrict__ out) {
    int b = threadIdx.x;
    if (b >= 64) return;
    float c[11];
    #pragma unroll
    for (int i = 0; i < 11; ++i) c[i] = coeffs[b * 11 + i];
    float h[4];
    #pragma unroll
    for (int k = 0; k < 4; ++k) {
        float s = b1[k];
        #pragma unroll
        for (int i = 0; i < 11; ++i) s += w1[k * 11 + i] * c[i];
        h[k] = fmaxf(s, 0.f);
    }
    #pragma unroll
    for (int o = 0; o < 10; ++o) {
        float s = b2[o];
        #pragma unroll
        for (int k = 0; k < 4; ++k) s += w2[o * 4 + k] * h[k];
        out[b * 10 + o] = 1.f / (1.f + expf(-s));
    }
}

extern "C" void kernel_launch(void* const* d_in, const int* in_sizes, int n_in,
                              void* d_out, int out_size, void* d_ws, size_t ws_size,
                              hipStream_t stream) {
    const float* img = (const float*)d_in[0];
    const float* w1  = (const float*)d_in[1];
    const float* b1  = (const float*)d_in[2];
    const float* w2  = (const float*)d_in[3];
    const float* b2  = (const float*)d_in[4];
    float* out = (float*)d_out;

    // workspace layout (floats): psi[16*16384] | ihat[64*16384 float2] | coeffs[64*11]
    float*  ws     = (float*)d_ws;
    float*  psi    = ws;
    float2* ihat   = (float2*)(ws + 16 * NPIX);
    float*  coeffs = ws + 16 * NPIX + 2 * 64 * NPIX;

    hipLaunchKernelGGL(k_pre,     dim3(81),   dim3(TT), 0, stream, img, psi, ihat, coeffs);
    hipLaunchKernelGGL(k_scatter, dim3(1024), dim3(TT), 0, stream, ihat, psi, coeffs);
    hipLaunchKernelGGL(k_mlp,     dim3(1),    dim3(64), 0, stream, coeffs, w1, b1, w2, b2, out);
}

// Round 14
// 241.185 us; speedup vs baseline: 1.5036x; 1.0435x over previous
//
#include <hip/hip_runtime.h>
#include <math.h>

#define NN   128
#define SS   129          // LDS row stride in float2 (ODD -> conflict-free lane stride)
#define TT   512          // PROVEN: TT=512 allocates ~112-128 VGPR no-spill (R4/R6-R13);
                          // TT=1024 ALWAYS gets 64 VGPR + spill (R2/R3/R10). Never 1024.
#define NPIX 16384        // 128*128
#define EPT  32           // NPIX / TT
#define SG   65           // 64-grid row stride (float2 or float4 units)
#define SG32 33           // 32-grid row stride

// R12 lesson: NO __threadfence() tail / in-kernel MLP fold (cost ~115 us).

__device__ __forceinline__ float2 cmul(float2 a, float2 w) {
    return make_float2(a.x * w.x - a.y * w.y, a.x * w.y + a.y * w.x);
}
__device__ __forceinline__ float2 cmulc(float2 a, float2 w) {   // a * conj(w)
    return make_float2(a.x * w.x + a.y * w.y, a.y * w.x - a.x * w.y);
}

// ---------- register FFT codelets (fft8/fft16 verified R2-R13) ----------
template<int SGN>
__device__ __forceinline__ void fft4(float2* f) {
    float2 t0 = make_float2(f[0].x + f[2].x, f[0].y + f[2].y);
    float2 t1 = make_float2(f[0].x - f[2].x, f[0].y - f[2].y);
    float2 t2 = make_float2(f[1].x + f[3].x, f[1].y + f[3].y);
    float2 t3 = make_float2(f[1].x - f[3].x, f[1].y - f[3].y);
    float2 t3i = (SGN > 0) ? make_float2(-t3.y, t3.x) : make_float2(t3.y, -t3.x);
    f[0] = make_float2(t0.x + t2.x, t0.y + t2.y);
    f[1] = make_float2(t1.x + t3i.x, t1.y + t3i.y);
    f[2] = make_float2(t0.x - t2.x, t0.y - t2.y);
    f[3] = make_float2(t1.x - t3i.x, t1.y - t3i.y);
}

template<int SGN>
__device__ __forceinline__ void fft8(float2* f) {
    const float R = 0.70710678118654752f;
    const float WC[4] = {1.f, R, 0.f, -R};
    const float WS[4] = {0.f, R, 1.f, R};
    #pragma unroll
    for (int stage = 0; stage < 3; ++stage) {
        const int L = 8 >> stage, half = L >> 1, step = 1 << stage;
        #pragma unroll
        for (int base = 0; base < 8; base += L) {
            #pragma unroll
            for (int j = 0; j < half; ++j) {
                float2 u = f[base + j], v = f[base + half + j];
                f[base + j] = make_float2(u.x + v.x, u.y + v.y);
                float dx = u.x - v.x, dy = u.y - v.y;
                const int t = j * step;
                const float wr = WC[t];
                const float wi = (SGN > 0) ? WS[t] : -WS[t];
                f[base + half + j] = make_float2(dx * wr - dy * wi, dx * wi + dy * wr);
            }
        }
    }
    float2 tmp;
    tmp = f[1]; f[1] = f[4]; f[4] = tmp;
    tmp = f[3]; f[3] = f[6]; f[6] = tmp;
}

template<int SGN>
__device__ __forceinline__ void fft16(float2* f) {
    const float WC[8] = {1.f, 0.92387953251f, 0.70710678119f, 0.38268343236f,
                         0.f, -0.38268343236f, -0.70710678119f, -0.92387953251f};
    const float WS[8] = {0.f, 0.38268343236f, 0.70710678119f, 0.92387953251f,
                         1.f, 0.92387953251f, 0.70710678119f, 0.38268343236f};
    #pragma unroll
    for (int stage = 0; stage < 4; ++stage) {
        const int L = 16 >> stage, half = L >> 1, step = 1 << stage;
        #pragma unroll
        for (int base = 0; base < 16; base += L) {
            #pragma unroll
            for (int j = 0; j < half; ++j) {
                float2 u = f[base + j], v = f[base + half + j];
                f[base + j] = make_float2(u.x + v.x, u.y + v.y);
                float dx = u.x - v.x, dy = u.y - v.y;
                const int t = j * step;
                const float wr = WC[t];
                const float wi = (SGN > 0) ? WS[t] : -WS[t];
                f[base + half + j] = make_float2(dx * wr - dy * wi, dx * wi + dy * wr);
            }
        }
    }
    float2 tmp;
    tmp = f[1];  f[1]  = f[8];  f[8]  = tmp;
    tmp = f[2];  f[2]  = f[4];  f[4]  = tmp;
    tmp = f[3];  f[3]  = f[12]; f[12] = tmp;
    tmp = f[5];  f[5]  = f[10]; f[10] = tmp;
    tmp = f[7];  f[7]  = f[14]; f[14] = tmp;
    tmp = f[11]; f[11] = f[13]; f[13] = tmp;
}

__device__ __forceinline__ float waveReduceSum(float v) {
    #pragma unroll
    for (int off = 32; off > 0; off >>= 1) v += __shfl_down(v, off, 64);
    return v;
}

__device__ __forceinline__ void buildTw(float2* tw, int tid) {
    if (tid < 128) {
        float s, c;
        __sincosf((float)tid * 0.04908738521234052f, &s, &c);   // 2*pi/128
        tw[tid] = make_float2(c, s);
    }
}

// ======== 128-grid sweep phases (R6-R13 proven, TT=512) ========
template<int ES, int LS>
__device__ __forceinline__ void fwdA(float2* __restrict__ F,
                                     const float2* __restrict__ tw, int tid) {
    #pragma unroll
    for (int i = 0; i < 4; ++i) {
        int u = i * TT + tid;
        int t = u >> 7, x = u & 127;
        float2* M = F + x * LS;
        float2 f[8];
        #pragma unroll
        for (int n1 = 0; n1 < 8; ++n1) f[n1] = M[(t + 16 * n1) * ES];
        fft8<-1>(f);
        #pragma unroll
        for (int ka = 0; ka < 8; ++ka)
            M[(t + 16 * ka) * ES] = cmulc(f[ka], tw[t * ka]);
    }
}

template<int ES, int LS>
__device__ __forceinline__ void fwdB(float2* __restrict__ F, int tid) {
    #pragma unroll
    for (int i = 0; i < 2; ++i) {
        int u = i * TT + tid;
        int ka = u >> 7, x = u & 127;
        float2* M = F + x * LS;
        float2 g[16];
        #pragma unroll
        for (int t = 0; t < 16; ++t) g[t] = M[(16 * ka + t) * ES];
        fft16<-1>(g);
        #pragma unroll
        for (int kb = 0; kb < 16; ++kb) M[(16 * ka + kb) * ES] = g[kb];
    }
}

__device__ __forceinline__ void fwdB_col_capture(const float2* __restrict__ F, int tid,
                                                 float2* __restrict__ uh) {
    #pragma unroll
    for (int i = 0; i < 2; ++i) {
        int u = i * TT + tid;
        int ka = u >> 7, c = u & 127;
        float2 g[16];
        #pragma unroll
        for (int t = 0; t < 16; ++t) g[t] = F[(16 * ka + t) * SS + c];
        fft16<-1>(g);
        #pragma unroll
        for (int kb = 0; kb < 16; ++kb) uh[i * 16 + kb] = g[kb];
    }
}

template<int ES, int LS>
__device__ __forceinline__ void invA(float2* __restrict__ F,
                                     const float2* __restrict__ tw, int tid) {
    #pragma unroll
    for (int i = 0; i < 2; ++i) {
        int u = i * TT + tid;
        int ka = u >> 7, x = u & 127;
        float2* M = F + x * LS;
        float2 g[16];
        #pragma unroll
        for (int kb = 0; kb < 16; ++kb) g[kb] = M[(16 * ka + kb) * ES];
        fft16<1>(g);
        #pragma unroll
        for (int t = 0; t < 16; ++t)
            M[(16 * ka + t) * ES] = cmul(g[t], tw[t * ka]);
    }
}

template<int ES, int LS>
__device__ __forceinline__ void invB(float2* __restrict__ F, int tid) {
    #pragma unroll
    for (int i = 0; i < 4; ++i) {
        int u = i * TT + tid;
        int t = u >> 7, x = u & 127;
        float2* M = F + x * LS;
        float2 f[8];
        #pragma unroll
        for (int ka = 0; ka < 8; ++ka) f[ka] = M[(16 * ka + t) * ES];
        fft8<1>(f);
        #pragma unroll
        for (int nh = 0; nh < 8; ++nh) M[(t + 16 * nh) * ES] = f[nh];
    }
}

__device__ __forceinline__ void invB_mag_row(float2* __restrict__ F, int tid, float& acc) {
    #pragma unroll
    for (int i = 0; i < 4; ++i) {
        int u = i * TT + tid;
        int t = u >> 7, x = u & 127;
        float2* M = F + x * SS;
        float2 f[8];
        #pragma unroll
        for (int ka = 0; ka < 8; ++ka) f[ka] = M[16 * ka + t];
        fft8<1>(f);
        #pragma unroll
        for (int nh = 0; nh < 8; ++nh)
            acc += sqrtf(f[nh].x * f[nh].x + f[nh].y * f[nh].y);
    }
}

// FUSED: inverse row stepB -> |.| (raw, acc) -> forward row stepA (same cells).
__device__ __forceinline__ void invBmag_fwdA_row(float2* __restrict__ F,
                                                 const float2* __restrict__ tw,
                                                 int tid, float& acc) {
    #pragma unroll
    for (int i = 0; i < 4; ++i) {
        int u = i * TT + tid;
        int t = u >> 7, x = u & 127;
        float2* M = F + x * SS;
        float2 f[8];
        #pragma unroll
        for (int ka = 0; ka < 8; ++ka) f[ka] = M[16 * ka + t];
        fft8<1>(f);
        #pragma unroll
        for (int nh = 0; nh < 8; ++nh) {
            float m = sqrtf(f[nh].x * f[nh].x + f[nh].y * f[nh].y);
            acc += m;
            f[nh] = make_float2(m, 0.f);
        }
        fft8<-1>(f);
        #pragma unroll
        for (int ka = 0; ka < 8; ++ka)
            M[t + 16 * ka] = cmulc(f[ka], tw[t * ka]);
    }
}

// ---------- K_pre: fused filter bank + coeff zero + i_hat FFT ----------
__global__ __attribute__((amdgpu_flat_work_group_size(TT, TT), amdgpu_waves_per_eu(2, 2)))
void k_pre(const float* __restrict__ img,
           float* __restrict__ psi,
           float2* __restrict__ ihat,
           float* __restrict__ coeffs) {
    __shared__ float2 F[NN * SS];
    __shared__ float2 tw[128];
    __shared__ float red[TT / 64];
    int blk = blockIdx.x, tid = threadIdx.x;
    if (blk >= 64) {
        if (blk == 80) {
            for (int i = tid; i < 64 * 11; i += TT)
                if (i % 11 != 0) coeffs[i] = 0.f;
            return;
        }
        int f = blk - 64;
        int j = f >> 2, l = f & 3;
        float k0    = 2.35619449019234493f / (float)(1 << j);
        float sigma = 0.8f * (float)(1 << j);
        float s2    = sigma * sigma;
        float theta = 0.78539816339744831f * (float)l;
        float k0x = k0 * cosf(theta);
        float k0y = k0 * sinf(theta);
        float beta = expf(-0.5f * s2 * k0 * k0);
        const float FSTEP = 0.04908738521234052f;
        float* dst = psi + (size_t)f * NPIX;
        for (int i = tid; i < NPIX; i += TT) {
            int pr = i >> 7, pc = i & 127;
            int kr = (pr >> 4) + 8 * (pr & 15);
            int kc = (pc >> 4) + 8 * (pc & 15);
            float fr = (float)(kr < 64 ? kr : kr - 128) * FSTEP;
            float fc = (float)(kc < 64 ? kc : kc - 128) * FSTEP;
            float dx = fr - k0x, dy = fc - k0y;
            float g1 = expf(-0.5f * s2 * (dx * dx + dy * dy));
            float g0 = expf(-0.5f * s2 * (fr * fr + fc * fc));
            dst[i] = g1 - beta * g0;
        }
        return;
    }
    int b = blk;
    buildTw(tw, tid);
    const float* im = img + (size_t)b * NPIX;
    float acc = 0.f;
    #pragma unroll
    for (int k = 0; k < EPT; ++k) {
        int e = k * TT + tid;
        float v = im[e];
        acc += v;
        F[(e >> 7) * SS + (e & 127)] = make_float2(v, 0.f);
    }
    float ws = waveReduceSum(acc);
    if ((tid & 63) == 0) red[tid >> 6] = ws;
    __syncthreads();
    if (tid == 0) {
        float t = 0.f;
        #pragma unroll
        for (int w = 0; w < TT / 64; ++w) t += red[w];
        coeffs[b * 11 + 0] = t * (1.f / 16384.f);
    }
    fwdA<1, SS>(F, tw, tid);  __syncthreads();
    fwdB<1, SS>(F, tid);      __syncthreads();
    fwdA<SS, 1>(F, tw, tid);  __syncthreads();
    float2 uh[32];
    fwdB_col_capture(F, tid, uh);
    float2* dst = ihat + (size_t)b * NPIX;
    #pragma unroll
    for (int i = 0; i < 2; ++i) {
        int u = i * TT + tid;
        int ka = u >> 7, c = u & 127;
        #pragma unroll
        for (int kb = 0; kb < 16; ++kb)
            dst[(16 * ka + kb) * NN + c] = uh[i * 16 + kb];
    }
}

// ---------- K_scat_big: j1 in {0,1} (full 128-grid; R13 verbatim) ----------
__global__ __attribute__((amdgpu_flat_work_group_size(TT, TT), amdgpu_waves_per_eu(2, 2)))
void k_scat_big(const float2* __restrict__ ihat,
                const float* __restrict__ psi,
                float* __restrict__ coeffs) {
    __shared__ __align__(16) float2 F[NN * SS];
    __shared__ float2 tw[128];
    float4* G4 = (float4*)F;
    float2* H  = F + 8320;
    int tid = threadIdx.x;
    int x = blockIdx.x;
    int b = x & 63, l1 = (x >> 6) & 3, j1 = x >> 8;    // j1 in {0,1}
    const float2* ih = ihat + (size_t)b * NPIX;
    const float*  p1 = psi + (size_t)(j1 * 4 + l1) * NPIX;
    buildTw(tw, tid);

    const float S1_128 = 9.3132257461547852e-10f;   // 2^-30
    const float S2FULL = 1.4210854715202004e-14f;   // 2^-46
    const float S2TR   = 5.6843418860808015e-14f;   // 2^-44

    int kalo = tid >> 7, c = tid & 127;
    {
        #pragma unroll
        for (int i = 0; i < 2; ++i) {
            int ka = kalo + 4 * i;
            float2 g[16];
            #pragma unroll
            for (int kb = 0; kb < 16; ++kb) {
                int e = (16 * ka + kb) * NN + c;
                float2 z = ih[e];
                float  p = p1[e];
                g[kb] = make_float2(z.x * p, z.y * p);
            }
            fft16<1>(g);
            #pragma unroll
            for (int t = 0; t < 16; ++t)
                F[(16 * ka + t) * SS + c] = cmul(g[t], tw[t * ka]);
        }
    }
    __syncthreads();
    invB<SS, 1>(F, tid);      __syncthreads();
    invA<1, SS>(F, tw, tid);  __syncthreads();
    float acc = 0.f;
    invBmag_fwdA_row(F, tw, tid, acc);
    float ws1 = waveReduceSum(acc);
    if ((tid & 63) == 0) atomicAdd(&coeffs[b * 11 + 1 + j1], ws1 * S1_128);
    __syncthreads();
    fwdB<1, SS>(F, tid);      __syncthreads();
    fwdA<SS, 1>(F, tw, tid);  __syncthreads();
    float2 uh[32];
    fwdB_col_capture(F, tid, uh);

    int m = c & 15;
    bool colKeep = (m < 4) || (m >= 12);
    int pc64 = 8 * (c >> 4) + ((m < 4) ? m : (m - 8));

    if (j1 == 0) {
        for (int it = 0; it < 4; ++it) {
            const float* p2 = psi + (size_t)(4 + it) * NPIX;
            #pragma unroll
            for (int i = 0; i < 2; ++i) {
                int ka = kalo + 4 * i;
                float2 g[16];
                #pragma unroll
                for (int kb = 0; kb < 16; ++kb) {
                    float p = p2[(16 * ka + kb) * NN + c];
                    float2 z = uh[i * 16 + kb];
                    g[kb] = make_float2(z.x * p, z.y * p);
                }
                fft16<1>(g);
                #pragma unroll
                for (int t = 0; t < 16; ++t)
                    F[(16 * ka + t) * SS + c] = cmul(g[t], tw[t * ka]);
            }
            __syncthreads();
            invB<SS, 1>(F, tid);      __syncthreads();
            invA<1, SS>(F, tw, tid);  __syncthreads();
            float a2 = 0.f;
            invB_mag_row(F, tid, a2);
            float ws2 = waveReduceSum(a2);
            if ((tid & 63) == 0) atomicAdd(&coeffs[b * 11 + 5 + 0], ws2 * S2FULL);
            __syncthreads();
        }
    } else {
        __syncthreads();
    }

    if (colKeep) {
        #pragma unroll
        for (int i = 0; i < 2; ++i) {
            int ka = kalo + 4 * i;
            #pragma unroll
            for (int kb = 0; kb < 16; ++kb) {
                if (kb < 4 || kb >= 12) {
                    int pr64 = 8 * ka + ((kb < 4) ? kb : (kb - 8));
                    H[pr64 * 64 + pc64] = uh[i * 16 + kb];
                }
            }
        }
    }
    __syncthreads();

    for (int j2 = 2; j2 <= 3; ++j2) {
        int pair = (j1 == 0) ? (j2 - 1) : (j2 + 1);
        for (int half = 0; half < 2; ++half) {
            const float* p2a = psi + (size_t)(j2 * 4 + 2 * half) * NPIX;
            const float* p2b = p2a + NPIX;
            if (colKeep) {
                #pragma unroll
                for (int i = 0; i < 2; ++i) {
                    int ka = kalo + 4 * i;
                    #pragma unroll
                    for (int kb = 0; kb < 16; ++kb) {
                        if (kb < 4 || kb >= 12) {
                            int pr64 = 8 * ka + ((kb < 4) ? kb : (kb - 8));
                            float2 z = H[pr64 * 64 + pc64];
                            int e = (16 * ka + kb) * NN + c;
                            float pa = p2a[e], pb = p2b[e];
                            G4[pr64 * SG + pc64] =
                                make_float4(z.x * pa, z.y * pa, z.x * pb, z.y * pb);
                        }
                    }
                }
            }
            __syncthreads();
            {   // col stepA
                int col = tid & 63, k8 = tid >> 6;
                float2 f0[8], f1[8];
                #pragma unroll
                for (int kb = 0; kb < 8; ++kb) {
                    float4 v = G4[(8 * k8 + kb) * SG + col];
                    f0[kb] = make_float2(v.x, v.y); f1[kb] = make_float2(v.z, v.w);
                }
                fft8<1>(f0); fft8<1>(f1);
                #pragma unroll
                for (int q = 0; q < 8; ++q) {
                    float2 w = tw[2 * q * k8];
                    float2 a = cmul(f0[q], w), d = cmul(f1[q], w);
                    G4[(8 * k8 + q) * SG + col] = make_float4(a.x, a.y, d.x, d.y);
                }
            }
            __syncthreads();
            {   // col stepB
                int col = tid & 63, q = tid >> 6;
                float2 f0[8], f1[8];
                #pragma unroll
                for (int k8 = 0; k8 < 8; ++k8) {
                    float4 v = G4[(8 * k8 + q) * SG + col];
                    f0[k8] = make_float2(v.x, v.y); f1[k8] = make_float2(v.z, v.w);
                }
                fft8<1>(f0); fft8<1>(f1);
                #pragma unroll
                for (int n1 = 0; n1 < 8; ++n1)
                    G4[(8 * n1 + q) * SG + col] =
                        make_float4(f0[n1].x, f0[n1].y, f1[n1].x, f1[n1].y);
            }
            __syncthreads();
            {   // row stepA
                int row = tid & 63, k8 = tid >> 6;
                float4* R = G4 + row * SG + 8 * k8;
                float2 f0[8], f1[8];
                #pragma unroll
                for (int kb = 0; kb < 8; ++kb) {
                    float4 v = R[kb];
                    f0[kb] = make_float2(v.x, v.y); f1[kb] = make_float2(v.z, v.w);
                }
                fft8<1>(f0); fft8<1>(f1);
                #pragma unroll
                for (int q = 0; q < 8; ++q) {
                    float2 w = tw[2 * q * k8];
                    float2 a = cmul(f0[q], w), d = cmul(f1[q], w);
                    R[q] = make_float4(a.x, a.y, d.x, d.y);
                }
            }
            __syncthreads();
            float a2 = 0.f;
            {   // row stepB + mag
                int row = tid & 63, q = tid >> 6;
                float4* R = G4 + row * SG + q;
                float2 f0[8], f1[8];
                #pragma unroll
                for (int k8 = 0; k8 < 8; ++k8) {
                    float4 v = R[8 * k8];
                    f0[k8] = make_float2(v.x, v.y); f1[k8] = make_float2(v.z, v.w);
                }
                fft8<1>(f0); fft8<1>(f1);
                #pragma unroll
                for (int n1 = 0; n1 < 8; ++n1) {
                    a2 += sqrtf(f0[n1].x * f0[n1].x + f0[n1].y * f0[n1].y);
                    a2 += sqrtf(f1[n1].x * f1[n1].x + f1[n1].y * f1[n1].y);
                }
            }
            float ws2 = waveReduceSum(a2);
            if ((tid & 63) == 0) atomicAdd(&coeffs[b * 11 + 5 + pair], ws2 * S2TR);
            __syncthreads();
        }
    }
}

// ---------- K_scat_small: j1 in {2,3} -- 43 KB LDS => 2+ blocks/CU ----------
__global__ __attribute__((amdgpu_flat_work_group_size(TT, TT), amdgpu_waves_per_eu(4, 4)))
void k_scat_small(const float2* __restrict__ ihat,
                  const float* __restrict__ psi,
                  float* __restrict__ coeffs) {
    // S layout: G2 = S[0..4160) (64x65); H32 = S[4160..5184) (32x32, perm32 freq);
    // G32 (single 32-grid, 32x33) and G32p (packed float4 32x33) alias S[0..).
    __shared__ __align__(16) float2 S[5184];
    __shared__ float2 tw[128];
    float2* G2  = S;
    float2* G32 = S;
    float4* G32p = (float4*)S;
    float2* H32 = S + 4160;
    int tid = threadIdx.x;
    int x = blockIdx.x;
    int b = x & 63, l1 = (x >> 6) & 3, j1 = 2 + (x >> 8);
    const float2* ih = ihat + (size_t)b * NPIX;
    const float*  p1 = psi + (size_t)(j1 * 4 + l1) * NPIX;
    buildTw(tw, tid);

    const float S1_64 = 3.7252902984619141e-9f;    // 2^-28
    const float S1_32 = 1.4901161193847656e-8f;    // 2^-26
    const float S2_32 = 9.0949470177292824e-13f;   // 2^-40

    int kalo = tid >> 7, c = tid & 127;

    if (j1 == 3) {
        // ===== 32-grid first order: psi_{j1=3} support +-16 (3.07 sigma margin) =====
        int m = c & 15;
        bool ck32 = (m < 2) || (m >= 14);
        int pc32 = 4 * (c >> 4) + ((m < 2) ? m : (m - 12));
        if (ck32) {
            #pragma unroll
            for (int i = 0; i < 2; ++i) {
                int ka = kalo + 4 * i;
                #pragma unroll
                for (int kb = 0; kb < 16; ++kb) {
                    if (kb < 2 || kb >= 14) {
                        int e = (16 * ka + kb) * NN + c;
                        float2 z = ih[e];
                        float  p = p1[e];
                        int pr32 = 4 * ka + ((kb < 2) ? kb : (kb - 12));
                        G32[pr32 * SG32 + pc32] = make_float2(z.x * p, z.y * p);
                    }
                }
            }
        }
        __syncthreads();
        if (tid < 256) {   // col stepA: fft4 over b per a (32 lines x 8 a)
            int line = tid & 31, a = tid >> 5;
            float2 f[4];
            #pragma unroll
            for (int kb = 0; kb < 4; ++kb) f[kb] = G32[(4 * a + kb) * SG32 + line];
            fft4<1>(f);
            #pragma unroll
            for (int t = 0; t < 4; ++t)
                G32[(4 * a + t) * SG32 + line] = cmul(f[t], tw[4 * t * a]);
        }
        __syncthreads();
        if (tid < 128) {   // col stepB: fft8 over a per t (32 lines x 4 t)
            int line = tid & 31, t = tid >> 5;
            float2 f[8];
            #pragma unroll
            for (int a = 0; a < 8; ++a) f[a] = G32[(4 * a + t) * SG32 + line];
            fft8<1>(f);
            #pragma unroll
            for (int n1 = 0; n1 < 8; ++n1) G32[(4 * n1 + t) * SG32 + line] = f[n1];
        }
        __syncthreads();
        if (tid < 256) {   // row stepA
            int row = tid & 31, a = tid >> 5;
            float2* R = G32 + row * SG32 + 4 * a;
            float2 f[4];
            #pragma unroll
            for (int kb = 0; kb < 4; ++kb) f[kb] = R[kb];
            fft4<1>(f);
            #pragma unroll
            for (int t = 0; t < 4; ++t) R[t] = cmul(f[t], tw[4 * t * a]);
        }
        __syncthreads();
        float acc = 0.f;
        if (tid < 128) {   // row stepB + mag
            int row = tid & 31, t = tid >> 5;
            float2* R = G32 + row * SG32 + t;
            float2 f[8];
            #pragma unroll
            for (int a = 0; a < 8; ++a) f[a] = R[4 * a];
            fft8<1>(f);
            #pragma unroll
            for (int n1 = 0; n1 < 8; ++n1)
                acc += sqrtf(f[n1].x * f[n1].x + f[n1].y * f[n1].y);
        }
        float ws1 = waveReduceSum(acc);
        if ((tid & 63) == 0 && tid < 128) atomicAdd(&coeffs[b * 11 + 4], ws1 * S1_32);
        return;
    }

    // ===================== j1 == 2: 64-grid first order (R13-proven) ==============
    int m = c & 15;
    bool colKeep = (m < 4) || (m >= 12);
    if (colKeep) {
        #pragma unroll
        for (int i = 0; i < 2; ++i) {
            int ka = kalo + 4 * i;
            #pragma unroll
            for (int kb = 0; kb < 16; ++kb) {
                if (kb < 4 || kb >= 12) {
                    int e = (16 * ka + kb) * NN + c;
                    float2 z = ih[e];
                    float  p = p1[e];
                    int pr64 = 8 * ka + ((kb < 4) ? kb : (kb - 8));
                    int pc64 = 8 * (c >> 4) + ((m < 4) ? m : (m - 8));
                    G2[pr64 * SG + pc64] = make_float2(z.x * p, z.y * p);
                }
            }
        }
    }
    __syncthreads();
    {   // col stepA (inverse)
        int col = tid & 63, k8 = tid >> 6;
        float2 f[8];
        #pragma unroll
        for (int kb = 0; kb < 8; ++kb) f[kb] = G2[(8 * k8 + kb) * SG + col];
        fft8<1>(f);
        #pragma unroll
        for (int q = 0; q < 8; ++q)
            G2[(8 * k8 + q) * SG + col] = cmul(f[q], tw[2 * q * k8]);
    }
    __syncthreads();
    {   // col stepB
        int col = tid & 63, q = tid >> 6;
        float2 f[8];
        #pragma unroll
        for (int k8 = 0; k8 < 8; ++k8) f[k8] = G2[(8 * k8 + q) * SG + col];
        fft8<1>(f);
        #pragma unroll
        for (int n1 = 0; n1 < 8; ++n1) G2[(8 * n1 + q) * SG + col] = f[n1];
    }
    __syncthreads();
    {   // row stepA (inverse)
        int row = tid & 63, k8 = tid >> 6;
        float2* R = G2 + row * SG + 8 * k8;
        float2 f[8];
        #pragma unroll
        for (int kb = 0; kb < 8; ++kb) f[kb] = R[kb];
        fft8<1>(f);
        #pragma unroll
        for (int q = 0; q < 8; ++q) R[q] = cmul(f[q], tw[2 * q * k8]);
    }
    __syncthreads();
    float acc = 0.f;
    {   // FUSED64: row stepB inv -> |.| (raw) -> row stepA fwd (same cells)
        int row = tid & 63, q = tid >> 6;
        float2* R = G2 + row * SG + q;
        float2 f[8];
        #pragma unroll
        for (int k8 = 0; k8 < 8; ++k8) f[k8] = R[8 * k8];
        fft8<1>(f);
        #pragma unroll
        for (int n1 = 0; n1 < 8; ++n1) {
            float mg = sqrtf(f[n1].x * f[n1].x + f[n1].y * f[n1].y);
            acc += mg;
            f[n1] = make_float2(mg, 0.f);
        }
        fft8<-1>(f);
        #pragma unroll
        for (int ka = 0; ka < 8; ++ka)
            R[8 * ka] = cmulc(f[ka], tw[2 * q * ka]);
    }
    float ws1 = waveReduceSum(acc);
    if ((tid & 63) == 0) atomicAdd(&coeffs[b * 11 + 3], ws1 * S1_64);
    __syncthreads();
    {   // row stepB (forward)
        int row2 = tid & 63, ka = tid >> 6;
        float2* R2 = G2 + row2 * SG + 8 * ka;
        float2 g[8];
        #pragma unroll
        for (int t = 0; t < 8; ++t) g[t] = R2[t];
        fft8<-1>(g);
        #pragma unroll
        for (int kb = 0; kb < 8; ++kb) R2[kb] = g[kb];
    }
    __syncthreads();
    {   // col stepA (forward)
        int col = tid & 63, t = tid >> 6;
        float2 g[8];
        #pragma unroll
        for (int n1 = 0; n1 < 8; ++n1) g[n1] = G2[(t + 8 * n1) * SG + col];
        fft8<-1>(g);
        #pragma unroll
        for (int ka = 0; ka < 8; ++ka)
            G2[(t + 8 * ka) * SG + col] = cmulc(g[ka], tw[2 * t * ka]);
    }
    __syncthreads();
    {   // col stepB (forward) -> H32: central +-16 of V only (perm32 layout)
        int col = tid & 63, ka = tid >> 6;
        float2 g[8];
        #pragma unroll
        for (int t = 0; t < 8; ++t) g[t] = G2[(8 * ka + t) * SG + col];
        fft8<-1>(g);
        int br = col & 7, ar = col >> 3;
        if (br < 2 || br >= 6) {
            int p32row = 4 * ar + (br & 3);
            #pragma unroll
            for (int kb = 0; kb < 8; ++kb) {
                if (kb < 2 || kb >= 6)
                    H32[(4 * ka + (kb & 3)) * 32 + p32row] = g[kb];
            }
        }
    }
    __syncthreads();

    // ===== truncated second order j2 = 3 on the 32-grid, 2 filters packed =====
    bool ck32 = (m < 2) || (m >= 14);
    int pc32 = 4 * (c >> 4) + ((m < 2) ? m : (m - 12));
    for (int half = 0; half < 2; ++half) {
        const float* p2a = psi + (size_t)(12 + 2 * half) * NPIX;
        const float* p2b = p2a + NPIX;
        if (ck32) {
            #pragma unroll
            for (int i = 0; i < 2; ++i) {
                int ka = kalo + 4 * i;
                #pragma unroll
                for (int kb = 0; kb < 16; ++kb) {
                    if (kb < 2 || kb >= 14) {
                        int pr32 = 4 * ka + ((kb < 2) ? kb : (kb - 12));
                        float2 z = H32[pr32 * 32 + pc32];
                        int e = (16 * ka + kb) * NN + c;
                        float pa = p2a[e], pb = p2b[e];
                        G32p[pr32 * SG32 + pc32] =
                            make_float4(z.x * pa, z.y * pa, z.x * pb, z.y * pb);
                    }
                }
            }
        }
        __syncthreads();
        if (tid < 256) {   // col stepA (packed)
            int line = tid & 31, a = tid >> 5;
            float2 f0[4], f1[4];
            #pragma unroll
            for (int kb = 0; kb < 4; ++kb) {
                float4 v = G32p[(4 * a + kb) * SG32 + line];
                f0[kb] = make_float2(v.x, v.y); f1[kb] = make_float2(v.z, v.w);
            }
            fft4<1>(f0); fft4<1>(f1);
            #pragma unroll
            for (int t = 0; t < 4; ++t) {
                float2 w = tw[4 * t * a];
                float2 aa = cmul(f0[t], w), d = cmul(f1[t], w);
                G32p[(4 * a + t) * SG32 + line] = make_float4(aa.x, aa.y, d.x, d.y);
            }
        }
        __syncthreads();
        if (tid < 128) {   // col stepB (packed)
            int line = tid & 31, t = tid >> 5;
            float2 f0[8], f1[8];
            #pragma unroll
            for (int a = 0; a < 8; ++a) {
                float4 v = G32p[(4 * a + t) * SG32 + line];
                f0[a] = make_float2(v.x, v.y); f1[a] = make_float2(v.z, v.w);
            }
            fft8<1>(f0); fft8<1>(f1);
            #pragma unroll
            for (int n1 = 0; n1 < 8; ++n1)
                G32p[(4 * n1 + t) * SG32 + line] =
                    make_float4(f0[n1].x, f0[n1].y, f1[n1].x, f1[n1].y);
        }
        __syncthreads();
        if (tid < 256) {   // row stepA (packed)
            int row = tid & 31, a = tid >> 5;
            float4* R = G32p + row * SG32 + 4 * a;
            float2 f0[4], f1[4];
            #pragma unroll
            for (int kb = 0; kb < 4; ++kb) {
                float4 v = R[kb];
                f0[kb] = make_float2(v.x, v.y); f1[kb] = make_float2(v.z, v.w);
            }
            fft4<1>(f0); fft4<1>(f1);
            #pragma unroll
            for (int t = 0; t < 4; ++t) {
                float2 w = tw[4 * t * a];
                float2 aa = cmul(f0[t], w), d = cmul(f1[t], w);
                R[t] = make_float4(aa.x, aa.y, d.x, d.y);
            }
        }
        __syncthreads();
        float a2 = 0.f;
        if (tid < 128) {   // row stepB + mag (packed)
            int row = tid & 31, t = tid >> 5;
            float4* R = G32p + row * SG32 + t;
            float2 f0[8], f1[8];
            #pragma unroll
            for (int a = 0; a < 8; ++a) {
                float4 v = R[4 * a];
                f0[a] = make_float2(v.x, v.y); f1[a] = make_float2(v.z, v.w);
            }
            fft8<1>(f0); fft8<1>(f1);
            #pragma unroll
            for (int n1 = 0; n1 < 8; ++n1) {
                a2 += sqrtf(f0[n1].x * f0[n1].x + f0[n1].y * f0[n1].y);
                a2 += sqrtf(f1[n1].x * f1[n1].x + f1[n1].y * f1[n1].y);
            }
        }
        float ws2 = waveReduceSum(a2);
        if ((tid & 63) == 0 && tid < 128)
            atomicAdd(&coeffs[b * 11 + 5 + 5], ws2 * S2_32);
        __syncthreads();
    }
}

// ---------- K_mlp: tiny MLP head (separate launch -- R12 lesson) ----------
__global__ void k_mlp(const float* __restrict__ coeffs,
                      const float* __restrict__ w1, const float* __restrict__ b1,
                      const float* __restrict__ w2, const float* __restrict__ b2,
                      float* __restrict__ out) {
    int b = threadIdx.x;
    if (b >= 64) return;
    float c[11];
    #pragma unroll
    for (int i = 0; i < 11; ++i) c[i] = coeffs[b * 11 + i];
    float h[4];
    #pragma unroll
    for (int k = 0; k < 4; ++k) {
        float s = b1[k];
        #pragma unroll
        for (int i = 0; i < 11; ++i) s += w1[k * 11 + i] * c[i];
        h[k] = fmaxf(s, 0.f);
    }
    #pragma unroll
    for (int o = 0; o < 10; ++o) {
        float s = b2[o];
        #pragma unroll
        for (int k = 0; k < 4; ++k) s += w2[o * 4 + k] * h[k];
        out[b * 10 + o] = 1.f / (1.f + expf(-s));
    }
}

extern "C" void kernel_launch(void* const* d_in, const int* in_sizes, int n_in,
                              void* d_out, int out_size, void* d_ws, size_t ws_size,
                              hipStream_t stream) {
    const float* img = (const float*)d_in[0];
    const float* w1  = (const float*)d_in[1];
    const float* b1  = (const float*)d_in[2];
    const float* w2  = (const float*)d_in[3];
    const float* b2  = (const float*)d_in[4];
    float* out = (float*)d_out;

    float*  ws     = (float*)d_ws;
    float*  psi    = ws;
    float2* ihat   = (float2*)(ws + 16 * NPIX);
    float*  coeffs = ws + 16 * NPIX + 2 * 64 * NPIX;

    hipLaunchKernelGGL(k_pre,        dim3(81),  dim3(TT), 0, stream, img, psi, ihat, coeffs);
    hipLaunchKernelGGL(k_scat_big,   dim3(512), dim3(TT), 0, stream, ihat, psi, coeffs);
    hipLaunchKernelGGL(k_scat_small, dim3(512), dim3(TT), 0, stream, ihat, psi, coeffs);
    hipLaunchKernelGGL(k_mlp,        dim3(1),   dim3(64), 0, stream, coeffs, w1, b1, w2, b2, out);
}